// Round 1
// baseline (531.506 us; speedup 1.0000x reference)
//
#include <hip/hip_runtime.h>
#include <hip/hip_bf16.h>
#include <math.h>

#define SLEN 2048
#define DMODEL 2048
#define NH 32
#define NKV 8
#define HD 64
#define BATCH 2
#define MROWS (BATCH * SLEN)            // 4096
#define QKVN (NH * HD + 2 * NKV * HD)   // 3072

typedef __attribute__((ext_vector_type(8))) short bf16x8;
typedef __attribute__((ext_vector_type(4))) float f32x4;

__device__ __forceinline__ unsigned short f2bf(float f) {
  union { float f; unsigned u; } v; v.f = f;
  return (unsigned short)((v.u + 0x7FFFu + ((v.u >> 16) & 1u)) >> 16);
}
__device__ __forceinline__ float bf2f(unsigned short h) {
  union { unsigned u; float f; } v; v.u = ((unsigned)h) << 16;
  return v.f;
}

// ---------------------------------------------------------------------------
// GEMM: C[m,n] = sum_k A[m,k] * B[n,k]   (B^T form, both K-contiguous)
// A fp32 [M,K], B fp32 [N,K] (up to 3 segments along N), C fp32 [M,N].
// SPLIT=1: split-bf16 3-product for near-fp32 accuracy.
// Tile 128x128, BK=32, 4 waves (2x2), each wave 64x64 = 4x4 frags 16x16.
// ---------------------------------------------------------------------------
template <int SPLIT>
__global__ __launch_bounds__(256) void gemm_bt_kernel(
    const float* __restrict__ A,
    const float* __restrict__ B0, const float* __restrict__ B1,
    const float* __restrict__ B2, int seg1, int seg2,
    float* __restrict__ C, int M, int N, int K) {
  constexpr int NP = SPLIT ? 2 : 1;
  __shared__ unsigned short As[NP][128][40];  // pad to 40 (80B rows, 16B-mult)
  __shared__ unsigned short Bs[NP][128][40];

  const int tid = threadIdx.x;
  const int lane = tid & 63;
  const int wid = tid >> 6;
  const int g = lane >> 4;
  const int fr = lane & 15;
  const int m0 = blockIdx.x * 128;
  const int n0 = blockIdx.y * 128;

  const float* Bp; int nl;
  if (n0 >= seg2)      { Bp = B2; nl = n0 - seg2; }
  else if (n0 >= seg1) { Bp = B1; nl = n0 - seg1; }
  else                 { Bp = B0; nl = n0; }

  const int wm = (wid >> 1) * 64;
  const int wn = (wid & 1) * 64;
  const int srow = tid >> 3;        // 0..31
  const int scol = (tid & 7) * 4;   // 0..28

  f32x4 acc[4][4];
#pragma unroll
  for (int i = 0; i < 4; i++)
#pragma unroll
    for (int j = 0; j < 4; j++) acc[i][j] = (f32x4){0.f, 0.f, 0.f, 0.f};

  for (int kt = 0; kt < K; kt += 32) {
    __syncthreads();
#pragma unroll
    for (int p = 0; p < 4; ++p) {
      const int row = srow + p * 32;
      const float4 av = *(const float4*)&A[(size_t)(m0 + row) * K + kt + scol];
      const float4 bv = *(const float4*)&Bp[(size_t)(nl + row) * K + kt + scol];
      const unsigned short a0 = f2bf(av.x), a1 = f2bf(av.y), a2 = f2bf(av.z), a3 = f2bf(av.w);
      const unsigned short b0 = f2bf(bv.x), b1 = f2bf(bv.y), b2 = f2bf(bv.z), b3 = f2bf(bv.w);
      *(ushort4*)&As[0][row][scol] = make_ushort4(a0, a1, a2, a3);
      *(ushort4*)&Bs[0][row][scol] = make_ushort4(b0, b1, b2, b3);
      if (SPLIT) {
        *(ushort4*)&As[1][row][scol] = make_ushort4(
            f2bf(av.x - bf2f(a0)), f2bf(av.y - bf2f(a1)),
            f2bf(av.z - bf2f(a2)), f2bf(av.w - bf2f(a3)));
        *(ushort4*)&Bs[1][row][scol] = make_ushort4(
            f2bf(bv.x - bf2f(b0)), f2bf(bv.y - bf2f(b1)),
            f2bf(bv.z - bf2f(b2)), f2bf(bv.w - bf2f(b3)));
      }
    }
    __syncthreads();

    bf16x8 af[NP][4], bf[NP][4];
#pragma unroll
    for (int i = 0; i < 4; i++) {
#pragma unroll
      for (int pp = 0; pp < NP; ++pp) {
        af[pp][i] = *(const bf16x8*)&As[pp][wm + i * 16 + fr][g * 8];
        bf[pp][i] = *(const bf16x8*)&Bs[pp][wn + i * 16 + fr][g * 8];
      }
    }
#pragma unroll
    for (int i = 0; i < 4; i++)
#pragma unroll
      for (int j = 0; j < 4; j++) {
        acc[i][j] = __builtin_amdgcn_mfma_f32_16x16x32_bf16(af[0][i], bf[0][j], acc[i][j], 0, 0, 0);
        if (SPLIT) {
          acc[i][j] = __builtin_amdgcn_mfma_f32_16x16x32_bf16(af[0][i], bf[1][j], acc[i][j], 0, 0, 0);
          acc[i][j] = __builtin_amdgcn_mfma_f32_16x16x32_bf16(af[1][i], bf[0][j], acc[i][j], 0, 0, 0);
        }
      }
  }

#pragma unroll
  for (int i = 0; i < 4; i++)
#pragma unroll
    for (int j = 0; j < 4; j++)
#pragma unroll
      for (int r = 0; r < 4; r++)
        C[(size_t)(m0 + wm + i * 16 + g * 4 + r) * N + n0 + wn + j * 16 + fr] = acc[i][j][r];
}

// ---------------------------------------------------------------------------
// RoPE + cast for Q: qkv[.., h*64+d] -> qb[b][h][s][d] bf16, scale 1/8 folded.
// One thread per (b,h,s,pair).
// ---------------------------------------------------------------------------
__global__ __launch_bounds__(256) void rope_q_kernel(const float* __restrict__ qkv,
                                                     unsigned short* __restrict__ qb) {
  const int idx = blockIdx.x * 256 + threadIdx.x;  // 2^22 total
  const int j = idx & 31;
  const int s = (idx >> 5) & (SLEN - 1);
  const int h = (idx >> 16) & (NH - 1);
  const int b = idx >> 21;
  const float2 x = *(const float2*)&qkv[(size_t)(b * SLEN + s) * QKVN + h * HD + 2 * j];
  const float inv = expf(-0.14391156831f * (float)(2 * j));  // ln(1e4)/64
  const float ang = (float)s * inv;
  float sn, cs;
  sincosf(ang, &sn, &cs);
  const float o0 = (x.x * cs - x.y * sn) * 0.125f;
  const float o1 = (x.x * sn + x.y * cs) * 0.125f;
  const unsigned pk = (unsigned)f2bf(o0) | ((unsigned)f2bf(o1) << 16);
  *(unsigned*)&qb[((size_t)(b * NH + h) * SLEN + s) * HD + 2 * j] = pk;
}

// RoPE + cast for K: -> kb[b][kh][s][d] bf16 (no scale)
__global__ __launch_bounds__(256) void rope_k_kernel(const float* __restrict__ qkv,
                                                     unsigned short* __restrict__ kb) {
  const int idx = blockIdx.x * 256 + threadIdx.x;  // 2^20 total
  const int j = idx & 31;
  const int s = (idx >> 5) & (SLEN - 1);
  const int kh = (idx >> 16) & (NKV - 1);
  const int b = idx >> 19;
  const float2 x = *(const float2*)&qkv[(size_t)(b * SLEN + s) * QKVN + NH * HD + kh * HD + 2 * j];
  const float inv = expf(-0.14391156831f * (float)(2 * j));
  const float ang = (float)s * inv;
  float sn, cs;
  sincosf(ang, &sn, &cs);
  const float o0 = x.x * cs - x.y * sn;
  const float o1 = x.x * sn + x.y * cs;
  const unsigned pk = (unsigned)f2bf(o0) | ((unsigned)f2bf(o1) << 16);
  *(unsigned*)&kb[((size_t)(b * NKV + kh) * SLEN + s) * HD + 2 * j] = pk;
}

// V transpose + cast: qkv v-part -> vt[b][kh][d][s] bf16 (64x64 LDS tiles)
__global__ __launch_bounds__(256) void vcast_kernel(const float* __restrict__ qkv,
                                                    unsigned short* __restrict__ vt) {
  __shared__ float tile[64][65];
  const int tid = threadIdx.x;
  const int bi = blockIdx.x;  // 512 blocks: (b, kh, stile)
  const int st = bi & 31;
  const int kh = (bi >> 5) & 7;
  const int b = bi >> 8;
  const int r = tid >> 2;
  const int c0 = (tid & 3) * 16;
  const float* src = &qkv[(size_t)(b * SLEN + st * 64 + r) * QKVN + NH * HD + NKV * HD + kh * HD + c0];
#pragma unroll
  for (int i = 0; i < 16; i += 4) {
    const float4 v = *(const float4*)(src + i);
    tile[r][c0 + i] = v.x; tile[r][c0 + i + 1] = v.y;
    tile[r][c0 + i + 2] = v.z; tile[r][c0 + i + 3] = v.w;
  }
  __syncthreads();
  alignas(16) unsigned short tmp[16];
#pragma unroll
  for (int i = 0; i < 16; ++i) tmp[i] = f2bf(tile[c0 + i][r]);
  unsigned short* dst = &vt[((size_t)(b * NKV + kh) * HD + r) * SLEN + st * 64 + c0];
  *(bf16x8*)dst = *(bf16x8*)tmp;
  *(bf16x8*)(dst + 8) = *(bf16x8*)(tmp + 8);
}

// ---------------------------------------------------------------------------
// Flash attention: grid (32 q-tiles, 64 b*h). 4 waves x 16 q-rows.
// K/V tiles of 64 keys in LDS; online softmax; P through LDS; PV MFMA.
// ---------------------------------------------------------------------------
__global__ __launch_bounds__(256) void attn_kernel(
    const unsigned short* __restrict__ qb, const unsigned short* __restrict__ kb,
    const unsigned short* __restrict__ vt, float* __restrict__ ao) {
  __shared__ unsigned short Kl[64][72];
  __shared__ unsigned short Vl[64][72];
  __shared__ unsigned short Pl[4][16][72];

  const int tid = threadIdx.x;
  const int lane = tid & 63;
  const int wid = tid >> 6;
  const int g = lane >> 4;
  const int fr = lane & 15;

  const int qt = blockIdx.x;
  const int bh = blockIdx.y;
  const int b = bh >> 5, h = bh & 31;
  const int kh = h >> 2;
  const size_t qbase = (size_t)bh * SLEN * HD;
  const size_t kbase = (size_t)(b * NKV + kh) * SLEN * HD;
  const size_t vbase = (size_t)(b * NKV + kh) * HD * SLEN;

  const int qrow = qt * 64 + wid * 16 + fr;
  const bf16x8 q0 = *(const bf16x8*)&qb[qbase + (size_t)qrow * HD + g * 8];
  const bf16x8 q1 = *(const bf16x8*)&qb[qbase + (size_t)qrow * HD + 32 + g * 8];

  f32x4 acc[4];
#pragma unroll
  for (int i = 0; i < 4; i++) acc[i] = (f32x4){0.f, 0.f, 0.f, 0.f};
  float mrow[4], lrow[4];
#pragma unroll
  for (int r = 0; r < 4; r++) { mrow[r] = -INFINITY; lrow[r] = 0.f; }

  const int trow = tid >> 2;
  const int tcol = (tid & 3) * 16;

  for (int kt = 0; kt < SLEN / 64; ++kt) {
    __syncthreads();
    {
      const int key = kt * 64 + trow;
      *(bf16x8*)&Kl[trow][tcol] = *(const bf16x8*)&kb[kbase + (size_t)key * HD + tcol];
      *(bf16x8*)&Kl[trow][tcol + 8] = *(const bf16x8*)&kb[kbase + (size_t)key * HD + tcol + 8];
      *(bf16x8*)&Vl[trow][tcol] = *(const bf16x8*)&vt[vbase + (size_t)trow * SLEN + kt * 64 + tcol];
      *(bf16x8*)&Vl[trow][tcol + 8] = *(const bf16x8*)&vt[vbase + (size_t)trow * SLEN + kt * 64 + tcol + 8];
    }
    __syncthreads();

    f32x4 sc[4];
#pragma unroll
    for (int j = 0; j < 4; j++) {
      const bf16x8 k0 = *(const bf16x8*)&Kl[j * 16 + fr][g * 8];
      const bf16x8 k1 = *(const bf16x8*)&Kl[j * 16 + fr][32 + g * 8];
      f32x4 s = (f32x4){0.f, 0.f, 0.f, 0.f};
      s = __builtin_amdgcn_mfma_f32_16x16x32_bf16(q0, k0, s, 0, 0, 0);
      s = __builtin_amdgcn_mfma_f32_16x16x32_bf16(q1, k1, s, 0, 0, 0);
      sc[j] = s;
    }

    float tm[4];
#pragma unroll
    for (int r = 0; r < 4; r++)
      tm[r] = fmaxf(fmaxf(sc[0][r], sc[1][r]), fmaxf(sc[2][r], sc[3][r]));
#pragma unroll
    for (int off = 1; off < 16; off <<= 1)
#pragma unroll
      for (int r = 0; r < 4; r++) tm[r] = fmaxf(tm[r], __shfl_xor(tm[r], off));

    float ps[4];
#pragma unroll
    for (int r = 0; r < 4; r++) {
      const float mn = fmaxf(mrow[r], tm[r]);
      const float corr = expf(mrow[r] - mn);
      lrow[r] *= corr;
#pragma unroll
      for (int dt = 0; dt < 4; ++dt) acc[dt][r] *= corr;
      float sum = 0.f;
#pragma unroll
      for (int j = 0; j < 4; j++) {
        const float p = expf(sc[j][r] - mn);
        sum += p;
        Pl[wid][g * 4 + r][j * 16 + fr] = f2bf(p);
      }
      ps[r] = sum;
      mrow[r] = mn;
    }
#pragma unroll
    for (int off = 1; off < 16; off <<= 1)
#pragma unroll
      for (int r = 0; r < 4; r++) ps[r] += __shfl_xor(ps[r], off);
#pragma unroll
    for (int r = 0; r < 4; r++) lrow[r] += ps[r];

    __syncthreads();

    const bf16x8 p0 = *(const bf16x8*)&Pl[wid][fr][g * 8];
    const bf16x8 p1 = *(const bf16x8*)&Pl[wid][fr][32 + g * 8];
#pragma unroll
    for (int dt = 0; dt < 4; ++dt) {
      const bf16x8 v0 = *(const bf16x8*)&Vl[dt * 16 + fr][g * 8];
      const bf16x8 v1 = *(const bf16x8*)&Vl[dt * 16 + fr][32 + g * 8];
      acc[dt] = __builtin_amdgcn_mfma_f32_16x16x32_bf16(p0, v0, acc[dt], 0, 0, 0);
      acc[dt] = __builtin_amdgcn_mfma_f32_16x16x32_bf16(p1, v1, acc[dt], 0, 0, 0);
    }
  }

#pragma unroll
  for (int dt = 0; dt < 4; ++dt)
#pragma unroll
    for (int r = 0; r < 4; ++r) {
      const int q = qt * 64 + wid * 16 + g * 4 + r;
      const int col = h * HD + dt * 16 + fr;
      ao[(size_t)(b * SLEN + q) * DMODEL + col] = acc[dt][r] / lrow[r];
    }
}

// ---------------------------------------------------------------------------
extern "C" void kernel_launch(void* const* d_in, const int* in_sizes, int n_in,
                              void* d_out, int out_size, void* d_ws, size_t ws_size,
                              hipStream_t stream) {
  const float* x  = (const float*)d_in[0];
  const float* Wq = (const float*)d_in[1];
  const float* Wk = (const float*)d_in[2];
  const float* Wv = (const float*)d_in[3];
  const float* Wo = (const float*)d_in[4];
  float* out = (float*)d_out;

  char* ws = (char*)d_ws;
  float* qkv = (float*)ws;               ws += (size_t)MROWS * QKVN * 4;        // 50.3 MB
  unsigned short* qb = (unsigned short*)ws; ws += (size_t)BATCH * NH * SLEN * HD * 2;   // 16.8 MB
  unsigned short* kb = (unsigned short*)ws; ws += (size_t)BATCH * NKV * SLEN * HD * 2;  // 4.2 MB
  unsigned short* vt = (unsigned short*)ws; ws += (size_t)BATCH * NKV * HD * SLEN * 2;  // 4.2 MB
  float* ao = (float*)ws;                                                       // 33.5 MB

  dim3 blk(256);

  // fused QKV projection: [4096,3072] = x[4096,2048] x [Wq;Wk;Wv]^T
  gemm_bt_kernel<0><<<dim3(MROWS / 128, QKVN / 128), blk, 0, stream>>>(
      x, Wq, Wk, Wv, NH * HD, NH * HD + NKV * HD, qkv, MROWS, QKVN, DMODEL);

  rope_q_kernel<<<(BATCH * NH * SLEN * 32) / 256, blk, 0, stream>>>(qkv, qb);
  rope_k_kernel<<<(BATCH * NKV * SLEN * 32) / 256, blk, 0, stream>>>(qkv, kb);
  vcast_kernel<<<BATCH * NKV * (SLEN / 64), blk, 0, stream>>>(qkv, vt);

  attn_kernel<<<dim3(SLEN / 64, BATCH * NH), blk, 0, stream>>>(qb, kb, vt, ao);

  // output projection (split-bf16, near-fp32): out = ao x Wo^T
  gemm_bt_kernel<1><<<dim3(MROWS / 128, DMODEL / 128), blk, 0, stream>>>(
      ao, Wo, Wo, Wo, 1 << 30, 1 << 30, out, MROWS, DMODEL, DMODEL);
}

// Round 2
// 397.080 us; speedup vs baseline: 1.3385x; 1.3385x over previous
//
#include <hip/hip_runtime.h>
#include <hip/hip_bf16.h>
#include <math.h>

#define SLEN 2048
#define DMODEL 2048
#define NH 32
#define NKV 8
#define HD 64
#define BATCH 2
#define MROWS (BATCH * SLEN)            // 4096
#define QKVN (NH * HD + 2 * NKV * HD)   // 3072

typedef __attribute__((ext_vector_type(8))) short bf16x8;
typedef __attribute__((ext_vector_type(4))) float f32x4;

__device__ __forceinline__ unsigned short f2bf(float f) {
  union { float f; unsigned u; } v; v.f = f;
  return (unsigned short)((v.u + 0x7FFFu + ((v.u >> 16) & 1u)) >> 16);
}
__device__ __forceinline__ float bf2f(unsigned short h) {
  union { unsigned u; float f; } v; v.u = ((unsigned)h) << 16;
  return v.f;
}
__device__ __forceinline__ unsigned cvt_pk_bf16(float lo, float hi) {
  unsigned r;
  asm("v_cvt_pk_bf16_f32 %0, %1, %2" : "=v"(r) : "v"(lo), "v"(hi));
  return r;
}
__device__ __forceinline__ float fast_exp2(float x) {
#if __has_builtin(__builtin_amdgcn_exp2f)
  return __builtin_amdgcn_exp2f(x);
#else
  return exp2f(x);
#endif
}

// ---------------------------------------------------------------------------
// GEMM: C[m,n] = sum_k A[m,k] * B[n,k]   (B^T form, both K-contiguous)
// A fp32 [M,K], B fp32 [N,K] (up to 3 segments along N), C fp32 [M,N].
// SPLIT=1: split-bf16 3-product for near-fp32 accuracy.
// Tile 128x128, BK=32, 4 waves (2x2), each wave 64x64 = 4x4 frags 16x16.
// ---------------------------------------------------------------------------
template <int SPLIT>
__global__ __launch_bounds__(256) void gemm_bt_kernel(
    const float* __restrict__ A,
    const float* __restrict__ B0, const float* __restrict__ B1,
    const float* __restrict__ B2, int seg1, int seg2,
    float* __restrict__ C, int M, int N, int K) {
  constexpr int NP = SPLIT ? 2 : 1;
  __shared__ unsigned short As[NP][128][40];  // pad to 40 (80B rows, 16B-mult)
  __shared__ unsigned short Bs[NP][128][40];

  const int tid = threadIdx.x;
  const int lane = tid & 63;
  const int wid = tid >> 6;
  const int g = lane >> 4;
  const int fr = lane & 15;
  const int m0 = blockIdx.x * 128;
  const int n0 = blockIdx.y * 128;

  const float* Bp; int nl;
  if (n0 >= seg2)      { Bp = B2; nl = n0 - seg2; }
  else if (n0 >= seg1) { Bp = B1; nl = n0 - seg1; }
  else                 { Bp = B0; nl = n0; }

  const int wm = (wid >> 1) * 64;
  const int wn = (wid & 1) * 64;
  const int srow = tid >> 3;        // 0..31
  const int scol = (tid & 7) * 4;   // 0..28

  f32x4 acc[4][4];
#pragma unroll
  for (int i = 0; i < 4; i++)
#pragma unroll
    for (int j = 0; j < 4; j++) acc[i][j] = (f32x4){0.f, 0.f, 0.f, 0.f};

  for (int kt = 0; kt < K; kt += 32) {
    __syncthreads();
#pragma unroll
    for (int p = 0; p < 4; ++p) {
      const int row = srow + p * 32;
      const float4 av = *(const float4*)&A[(size_t)(m0 + row) * K + kt + scol];
      const float4 bv = *(const float4*)&Bp[(size_t)(nl + row) * K + kt + scol];
      const unsigned short a0 = f2bf(av.x), a1 = f2bf(av.y), a2 = f2bf(av.z), a3 = f2bf(av.w);
      const unsigned short b0 = f2bf(bv.x), b1 = f2bf(bv.y), b2 = f2bf(bv.z), b3 = f2bf(bv.w);
      *(ushort4*)&As[0][row][scol] = make_ushort4(a0, a1, a2, a3);
      *(ushort4*)&Bs[0][row][scol] = make_ushort4(b0, b1, b2, b3);
      if (SPLIT) {
        *(ushort4*)&As[1][row][scol] = make_ushort4(
            f2bf(av.x - bf2f(a0)), f2bf(av.y - bf2f(a1)),
            f2bf(av.z - bf2f(a2)), f2bf(av.w - bf2f(a3)));
        *(ushort4*)&Bs[1][row][scol] = make_ushort4(
            f2bf(bv.x - bf2f(b0)), f2bf(bv.y - bf2f(b1)),
            f2bf(bv.z - bf2f(b2)), f2bf(bv.w - bf2f(b3)));
      }
    }
    __syncthreads();

    bf16x8 af[NP][4], bf[NP][4];
#pragma unroll
    for (int i = 0; i < 4; i++) {
#pragma unroll
      for (int pp = 0; pp < NP; ++pp) {
        af[pp][i] = *(const bf16x8*)&As[pp][wm + i * 16 + fr][g * 8];
        bf[pp][i] = *(const bf16x8*)&Bs[pp][wn + i * 16 + fr][g * 8];
      }
    }
#pragma unroll
    for (int i = 0; i < 4; i++)
#pragma unroll
      for (int j = 0; j < 4; j++) {
        acc[i][j] = __builtin_amdgcn_mfma_f32_16x16x32_bf16(af[0][i], bf[0][j], acc[i][j], 0, 0, 0);
        if (SPLIT) {
          acc[i][j] = __builtin_amdgcn_mfma_f32_16x16x32_bf16(af[0][i], bf[1][j], acc[i][j], 0, 0, 0);
          acc[i][j] = __builtin_amdgcn_mfma_f32_16x16x32_bf16(af[1][i], bf[0][j], acc[i][j], 0, 0, 0);
        }
      }
  }

#pragma unroll
  for (int i = 0; i < 4; i++)
#pragma unroll
    for (int j = 0; j < 4; j++)
#pragma unroll
      for (int r = 0; r < 4; r++)
        C[(size_t)(m0 + wm + i * 16 + g * 4 + r) * N + n0 + wn + j * 16 + fr] = acc[i][j][r];
}

// ---------------------------------------------------------------------------
// RoPE + cast for Q: qkv[.., h*64+d] -> qb[b][h][s][d] bf16.
// Scale (1/8)*log2(e) folded so attention softmax runs in exp2 domain.
// ---------------------------------------------------------------------------
__global__ __launch_bounds__(256) void rope_q_kernel(const float* __restrict__ qkv,
                                                     unsigned short* __restrict__ qb) {
  const int idx = blockIdx.x * 256 + threadIdx.x;  // 2^22 total
  const int j = idx & 31;
  const int s = (idx >> 5) & (SLEN - 1);
  const int h = (idx >> 16) & (NH - 1);
  const int b = idx >> 21;
  const float2 x = *(const float2*)&qkv[(size_t)(b * SLEN + s) * QKVN + h * HD + 2 * j];
  const float inv = expf(-0.14391156831f * (float)(2 * j));  // ln(1e4)/64
  const float ang = (float)s * inv;
  float sn, cs;
  sincosf(ang, &sn, &cs);
  const float SC = 0.18033688011f;  // 0.125 * log2(e)
  const float o0 = (x.x * cs - x.y * sn) * SC;
  const float o1 = (x.x * sn + x.y * cs) * SC;
  const unsigned pk = (unsigned)f2bf(o0) | ((unsigned)f2bf(o1) << 16);
  *(unsigned*)&qb[((size_t)(b * NH + h) * SLEN + s) * HD + 2 * j] = pk;
}

// RoPE + cast for K: -> kb[b][kh][s][d] bf16 (no scale)
__global__ __launch_bounds__(256) void rope_k_kernel(const float* __restrict__ qkv,
                                                     unsigned short* __restrict__ kb) {
  const int idx = blockIdx.x * 256 + threadIdx.x;  // 2^20 total
  const int j = idx & 31;
  const int s = (idx >> 5) & (SLEN - 1);
  const int kh = (idx >> 16) & (NKV - 1);
  const int b = idx >> 19;
  const float2 x = *(const float2*)&qkv[(size_t)(b * SLEN + s) * QKVN + NH * HD + kh * HD + 2 * j];
  const float inv = expf(-0.14391156831f * (float)(2 * j));
  const float ang = (float)s * inv;
  float sn, cs;
  sincosf(ang, &sn, &cs);
  const float o0 = x.x * cs - x.y * sn;
  const float o1 = x.x * sn + x.y * cs;
  const unsigned pk = (unsigned)f2bf(o0) | ((unsigned)f2bf(o1) << 16);
  *(unsigned*)&kb[((size_t)(b * NKV + kh) * SLEN + s) * HD + 2 * j] = pk;
}

// V transpose + cast: qkv v-part -> vt[b][kh][d][s] bf16 (64x64 LDS tiles)
__global__ __launch_bounds__(256) void vcast_kernel(const float* __restrict__ qkv,
                                                    unsigned short* __restrict__ vt) {
  __shared__ float tile[64][65];
  const int tid = threadIdx.x;
  const int bi = blockIdx.x;  // 512 blocks: (b, kh, stile)
  const int st = bi & 31;
  const int kh = (bi >> 5) & 7;
  const int b = bi >> 8;
  const int r = tid >> 2;
  const int c0 = (tid & 3) * 16;
  const float* src = &qkv[(size_t)(b * SLEN + st * 64 + r) * QKVN + NH * HD + NKV * HD + kh * HD + c0];
#pragma unroll
  for (int i = 0; i < 16; i += 4) {
    const float4 v = *(const float4*)(src + i);
    tile[r][c0 + i] = v.x; tile[r][c0 + i + 1] = v.y;
    tile[r][c0 + i + 2] = v.z; tile[r][c0 + i + 3] = v.w;
  }
  __syncthreads();
  alignas(16) unsigned short tmp[16];
#pragma unroll
  for (int i = 0; i < 16; ++i) tmp[i] = f2bf(tile[c0 + i][r]);
  unsigned short* dst = &vt[((size_t)(b * NKV + kh) * HD + r) * SLEN + st * 64 + c0];
  *(bf16x8*)dst = *(bf16x8*)tmp;
  *(bf16x8*)(dst + 8) = *(bf16x8*)(tmp + 8);
}

// ---------------------------------------------------------------------------
// Flash attention, swapped-operand in-register softmax.
// Grid (32 q-tiles, 64 b*h). 4 waves x 16 q-rows; each lane owns ONE q row
// (q = lane&15) and a 16-score register slice per 64-key tile.
// QK^T: sc = mfma(K, Q)  -> C[key][q]  (col=q=fr, row=key=j*16+g*4+r)
// PV  : O^T = mfma(V^T, P^T) -> C[d][q] (col=q=fr, row=d=dt*16+g*4+r)
// Softmax in exp2 domain (log2e/8 folded into Q), defer-max THR=8.
// P goes lane->LDS (per-wave, no barrier) as P[q][key] bf16, read as B-frag.
// ---------------------------------------------------------------------------
__global__ __launch_bounds__(256) void attn_kernel(
    const unsigned short* __restrict__ qb, const unsigned short* __restrict__ kb,
    const unsigned short* __restrict__ vt, float* __restrict__ ao) {
  __shared__ unsigned short Kl[64][72];       // [key][hd]
  __shared__ unsigned short Vl[64][72];       // [hd][key]  (V^T)
  __shared__ unsigned short Pq[4][16][72];    // per-wave P[q][key]

  const int tid = threadIdx.x;
  const int lane = tid & 63;
  const int wid = tid >> 6;
  const int g = lane >> 4;     // 0..3
  const int fr = lane & 15;    // this lane's q row (within wave)

  const int qt = blockIdx.x;
  const int bh = blockIdx.y;
  const int b = bh >> 5, h = bh & 31;
  const int kh = h >> 2;
  const size_t qbase = (size_t)bh * SLEN * HD;
  const size_t kbase = (size_t)(b * NKV + kh) * SLEN * HD;
  const size_t vbase = (size_t)(b * NKV + kh) * HD * SLEN;

  const int qrow = qt * 64 + wid * 16 + fr;
  const bf16x8 q0 = *(const bf16x8*)&qb[qbase + (size_t)qrow * HD + g * 8];
  const bf16x8 q1 = *(const bf16x8*)&qb[qbase + (size_t)qrow * HD + 32 + g * 8];

  f32x4 acc[4];   // acc[dt][r] = O^T[dt*16+g*4+r][q=fr]
#pragma unroll
  for (int i = 0; i < 4; i++) acc[i] = (f32x4){0.f, 0.f, 0.f, 0.f};
  float m = -1e30f, l = 0.f;

  const int trow = tid >> 2;        // 0..63
  const int tcol = (tid & 3) * 16;  // 0,16,32,48

  for (int kt = 0; kt < SLEN / 64; ++kt) {
    __syncthreads();
    {
      const int key = kt * 64 + trow;
      *(bf16x8*)&Kl[trow][tcol] = *(const bf16x8*)&kb[kbase + (size_t)key * HD + tcol];
      *(bf16x8*)&Kl[trow][tcol + 8] = *(const bf16x8*)&kb[kbase + (size_t)key * HD + tcol + 8];
      *(bf16x8*)&Vl[trow][tcol] = *(const bf16x8*)&vt[vbase + (size_t)trow * SLEN + kt * 64 + tcol];
      *(bf16x8*)&Vl[trow][tcol + 8] = *(const bf16x8*)&vt[vbase + (size_t)trow * SLEN + kt * 64 + tcol + 8];
    }
    __syncthreads();

    // ---- QK^T (swapped): per lane 16 scores for q=fr, keys j*16+g*4+r ----
    f32x4 sc[4];
#pragma unroll
    for (int j = 0; j < 4; j++) {
      const bf16x8 k0 = *(const bf16x8*)&Kl[j * 16 + fr][g * 8];
      const bf16x8 k1 = *(const bf16x8*)&Kl[j * 16 + fr][32 + g * 8];
      f32x4 s = (f32x4){0.f, 0.f, 0.f, 0.f};
      s = __builtin_amdgcn_mfma_f32_16x16x32_bf16(k0, q0, s, 0, 0, 0);
      s = __builtin_amdgcn_mfma_f32_16x16x32_bf16(k1, q1, s, 0, 0, 0);
      sc[j] = s;
    }

    // ---- in-register online softmax (exp2 domain) ----
    float t01 = fmaxf(fmaxf(sc[0][0], sc[0][1]), fmaxf(sc[0][2], sc[0][3]));
    float t23 = fmaxf(fmaxf(sc[1][0], sc[1][1]), fmaxf(sc[1][2], sc[1][3]));
    float t45 = fmaxf(fmaxf(sc[2][0], sc[2][1]), fmaxf(sc[2][2], sc[2][3]));
    float t67 = fmaxf(fmaxf(sc[3][0], sc[3][1]), fmaxf(sc[3][2], sc[3][3]));
    float tmax = fmaxf(fmaxf(t01, t23), fmaxf(t45, t67));
    tmax = fmaxf(tmax, __shfl_xor(tmax, 16));
    tmax = fmaxf(tmax, __shfl_xor(tmax, 32));

    if (__any(tmax > m + 8.0f)) {   // defer-max: rescale only on real growth
      const float mn = fmaxf(m, tmax);
      const float corr = fast_exp2(m - mn);
      l *= corr;
#pragma unroll
      for (int dt = 0; dt < 4; ++dt) acc[dt] *= corr;
      m = mn;
    }

    float p[4][4];
    float lsum = 0.f;
#pragma unroll
    for (int j = 0; j < 4; j++)
#pragma unroll
      for (int r = 0; r < 4; r++) {
        p[j][r] = fast_exp2(sc[j][r] - m);
        lsum += p[j][r];
      }
    lsum += __shfl_xor(lsum, 16);
    lsum += __shfl_xor(lsum, 32);
    l += lsum;

    // ---- pack P -> bf16, stage per-wave P[q][key] (no barrier needed) ----
#pragma unroll
    for (int j = 0; j < 4; j++) {
      *(unsigned*)&Pq[wid][fr][j * 16 + g * 4] = cvt_pk_bf16(p[j][0], p[j][1]);
      *(unsigned*)&Pq[wid][fr][j * 16 + g * 4 + 2] = cvt_pk_bf16(p[j][2], p[j][3]);
    }

    const bf16x8 pt0 = *(const bf16x8*)&Pq[wid][fr][g * 8];        // keys g*8..+7
    const bf16x8 pt1 = *(const bf16x8*)&Pq[wid][fr][32 + g * 8];   // keys 32+g*8..

    // ---- PV: O^T += V^T · P^T ----
#pragma unroll
    for (int dt = 0; dt < 4; ++dt) {
      const bf16x8 v0 = *(const bf16x8*)&Vl[dt * 16 + fr][g * 8];
      const bf16x8 v1 = *(const bf16x8*)&Vl[dt * 16 + fr][32 + g * 8];
      acc[dt] = __builtin_amdgcn_mfma_f32_16x16x32_bf16(v0, pt0, acc[dt], 0, 0, 0);
      acc[dt] = __builtin_amdgcn_mfma_f32_16x16x32_bf16(v1, pt1, acc[dt], 0, 0, 0);
    }
  }

  const float rl = 1.0f / l;
#pragma unroll
  for (int dt = 0; dt < 4; ++dt) {
    float4 o;
    o.x = acc[dt][0] * rl; o.y = acc[dt][1] * rl;
    o.z = acc[dt][2] * rl; o.w = acc[dt][3] * rl;
    *(float4*)&ao[(size_t)(b * SLEN + qrow) * DMODEL + h * HD + dt * 16 + g * 4] = o;
  }
}

// ---------------------------------------------------------------------------
extern "C" void kernel_launch(void* const* d_in, const int* in_sizes, int n_in,
                              void* d_out, int out_size, void* d_ws, size_t ws_size,
                              hipStream_t stream) {
  const float* x  = (const float*)d_in[0];
  const float* Wq = (const float*)d_in[1];
  const float* Wk = (const float*)d_in[2];
  const float* Wv = (const float*)d_in[3];
  const float* Wo = (const float*)d_in[4];
  float* out = (float*)d_out;

  char* ws = (char*)d_ws;
  float* qkv = (float*)ws;               ws += (size_t)MROWS * QKVN * 4;        // 50.3 MB
  unsigned short* qb = (unsigned short*)ws; ws += (size_t)BATCH * NH * SLEN * HD * 2;   // 16.8 MB
  unsigned short* kb = (unsigned short*)ws; ws += (size_t)BATCH * NKV * SLEN * HD * 2;  // 4.2 MB
  unsigned short* vt = (unsigned short*)ws; ws += (size_t)BATCH * NKV * HD * SLEN * 2;  // 4.2 MB
  float* ao = (float*)ws;                                                       // 33.5 MB

  dim3 blk(256);

  // fused QKV projection: [4096,3072] = x[4096,2048] x [Wq;Wk;Wv]^T
  gemm_bt_kernel<0><<<dim3(MROWS / 128, QKVN / 128), blk, 0, stream>>>(
      x, Wq, Wk, Wv, NH * HD, NH * HD + NKV * HD, qkv, MROWS, QKVN, DMODEL);

  rope_q_kernel<<<(BATCH * NH * SLEN * 32) / 256, blk, 0, stream>>>(qkv, qb);
  rope_k_kernel<<<(BATCH * NKV * SLEN * 32) / 256, blk, 0, stream>>>(qkv, kb);
  vcast_kernel<<<BATCH * NKV * (SLEN / 64), blk, 0, stream>>>(qkv, vt);

  attn_kernel<<<dim3(SLEN / 64, BATCH * NH), blk, 0, stream>>>(qb, kb, vt, ao);

  // output projection (split-bf16, near-fp32): out = ao x Wo^T
  gemm_bt_kernel<1><<<dim3(MROWS / 128, DMODEL / 128), blk, 0, stream>>>(
      ao, Wo, Wo, Wo, 1 << 30, 1 << 30, out, MROWS, DMODEL, DMODEL);
}

// Round 3
// 300.592 us; speedup vs baseline: 1.7682x; 1.3210x over previous
//
#include <hip/hip_runtime.h>
#include <hip/hip_bf16.h>
#include <math.h>

#define SLEN 2048
#define DMODEL 2048
#define NH 32
#define NKV 8
#define HD 64
#define BATCH 2
#define MROWS (BATCH * SLEN)            // 4096
#define QKVN (NH * HD + 2 * NKV * HD)   // 3072

typedef __attribute__((ext_vector_type(8))) short bf16x8;
typedef __attribute__((ext_vector_type(4))) float f32x4;

__device__ __forceinline__ unsigned short f2bf(float f) {
  union { float f; unsigned u; } v; v.f = f;
  return (unsigned short)((v.u + 0x7FFFu + ((v.u >> 16) & 1u)) >> 16);
}
__device__ __forceinline__ unsigned cvt_pk_bf16(float lo, float hi) {
  unsigned r;
  asm("v_cvt_pk_bf16_f32 %0, %1, %2" : "=v"(r) : "v"(lo), "v"(hi));
  return r;
}
__device__ __forceinline__ float fast_exp2(float x) {
#if __has_builtin(__builtin_amdgcn_exp2f)
  return __builtin_amdgcn_exp2f(x);
#else
  return exp2f(x);
#endif
}
// async global->LDS, 16B per lane: lane l writes lds_base + l*16
__device__ __forceinline__ void gload_lds16(const unsigned short* g, unsigned short* l) {
  __builtin_amdgcn_global_load_lds(
      (const __attribute__((address_space(1))) unsigned int*)(g),
      (__attribute__((address_space(3))) unsigned int*)(l), 16, 0, 0);
}

// ---------------------------------------------------------------------------
// fp32 -> bf16 streaming convert (8 elems/thread)
// ---------------------------------------------------------------------------
__global__ __launch_bounds__(256) void cvt_kernel(const float* __restrict__ src,
                                                  unsigned short* __restrict__ dst,
                                                  int n8) {
  const int i = blockIdx.x * 256 + threadIdx.x;
  if (i >= n8) return;
  const float4 a = *(const float4*)&src[(size_t)i * 8];
  const float4 b = *(const float4*)&src[(size_t)i * 8 + 4];
  uint4 o;
  o.x = cvt_pk_bf16(a.x, a.y);
  o.y = cvt_pk_bf16(a.z, a.w);
  o.z = cvt_pk_bf16(b.x, b.y);
  o.w = cvt_pk_bf16(b.z, b.w);
  *(uint4*)&dst[(size_t)i * 8] = o;
}

// ---------------------------------------------------------------------------
// bf16 GEMM (m97 structure): C[m,n] = sum_k A[m,k]*B[n,k], fp32 out.
// 128x128 tile, BK=32, 4 waves (2x2), global_load_lds(16) staging, 2-barrier.
// ---------------------------------------------------------------------------
__global__ __launch_bounds__(256) void gemm_bf16_kernel(
    const unsigned short* __restrict__ A, const unsigned short* __restrict__ B,
    float* __restrict__ C, int M, int N, int K) {
  __shared__ unsigned short As[128][32];
  __shared__ unsigned short Bs[128][32];

  const int tid = threadIdx.x;
  const int lane = tid & 63;
  const int wid = tid >> 6;
  const int g = lane >> 4;
  const int fr = lane & 15;
  const int m0 = blockIdx.x * 128;
  const int n0 = blockIdx.y * 128;
  const int wm = (wid >> 1) * 64;
  const int wn = (wid & 1) * 64;

  // staging: wave wid covers rows [wid*32, wid*32+32) in 2 instrs of 16 rows
  const int srow = wid * 32 + (lane >> 2);
  const int scol = (lane & 3) * 8;
  const unsigned short* ga = &A[(size_t)(m0 + srow) * K + scol];
  const unsigned short* gb = &B[(size_t)(n0 + srow) * K + scol];
  unsigned short* la0 = &As[wid * 32][0];
  unsigned short* la1 = &As[wid * 32 + 16][0];
  unsigned short* lb0 = &Bs[wid * 32][0];
  unsigned short* lb1 = &Bs[wid * 32 + 16][0];
  const size_t rstep = (size_t)16 * K;

  f32x4 acc[4][4];
#pragma unroll
  for (int i = 0; i < 4; i++)
#pragma unroll
    for (int j = 0; j < 4; j++) acc[i][j] = (f32x4){0.f, 0.f, 0.f, 0.f};

  for (int kt = 0; kt < K; kt += 32) {
    __syncthreads();
    gload_lds16(ga + kt, la0);
    gload_lds16(ga + kt + rstep, la1);
    gload_lds16(gb + kt, lb0);
    gload_lds16(gb + kt + rstep, lb1);
    __syncthreads();

    bf16x8 af[4], bfr[4];
#pragma unroll
    for (int i = 0; i < 4; i++) {
      af[i] = *(const bf16x8*)&As[wm + i * 16 + fr][g * 8];
      bfr[i] = *(const bf16x8*)&Bs[wn + i * 16 + fr][g * 8];
    }
#pragma unroll
    for (int i = 0; i < 4; i++)
#pragma unroll
      for (int j = 0; j < 4; j++)
        acc[i][j] = __builtin_amdgcn_mfma_f32_16x16x32_bf16(af[i], bfr[j], acc[i][j], 0, 0, 0);
  }

#pragma unroll
  for (int i = 0; i < 4; i++)
#pragma unroll
    for (int j = 0; j < 4; j++)
#pragma unroll
      for (int r = 0; r < 4; r++)
        C[(size_t)(m0 + wm + i * 16 + g * 4 + r) * N + n0 + wn + j * 16 + fr] = acc[i][j][r];
}

// ---------------------------------------------------------------------------
// RoPE + cast for Q: qkv[.., h*64+d] -> qb[b][h][s][d] bf16.
// Scale (1/8)*log2(e) folded so attention softmax runs in exp2 domain.
// ---------------------------------------------------------------------------
__global__ __launch_bounds__(256) void rope_q_kernel(const float* __restrict__ qkv,
                                                     unsigned short* __restrict__ qb) {
  const int idx = blockIdx.x * 256 + threadIdx.x;  // 2^22 total
  const int j = idx & 31;
  const int s = (idx >> 5) & (SLEN - 1);
  const int h = (idx >> 16) & (NH - 1);
  const int b = idx >> 21;
  const float2 x = *(const float2*)&qkv[(size_t)(b * SLEN + s) * QKVN + h * HD + 2 * j];
  const float inv = expf(-0.14391156831f * (float)(2 * j));  // ln(1e4)/64
  const float ang = (float)s * inv;
  float sn, cs;
  sincosf(ang, &sn, &cs);
  const float SC = 0.18033688011f;  // 0.125 * log2(e)
  const float o0 = (x.x * cs - x.y * sn) * SC;
  const float o1 = (x.x * sn + x.y * cs) * SC;
  const unsigned pk = (unsigned)f2bf(o0) | ((unsigned)f2bf(o1) << 16);
  *(unsigned*)&qb[((size_t)(b * NH + h) * SLEN + s) * HD + 2 * j] = pk;
}

// RoPE + cast for K: -> kb[b][kh][s][d] bf16 (no scale)
__global__ __launch_bounds__(256) void rope_k_kernel(const float* __restrict__ qkv,
                                                     unsigned short* __restrict__ kb) {
  const int idx = blockIdx.x * 256 + threadIdx.x;  // 2^20 total
  const int j = idx & 31;
  const int s = (idx >> 5) & (SLEN - 1);
  const int kh = (idx >> 16) & (NKV - 1);
  const int b = idx >> 19;
  const float2 x = *(const float2*)&qkv[(size_t)(b * SLEN + s) * QKVN + NH * HD + kh * HD + 2 * j];
  const float inv = expf(-0.14391156831f * (float)(2 * j));
  const float ang = (float)s * inv;
  float sn, cs;
  sincosf(ang, &sn, &cs);
  const float o0 = x.x * cs - x.y * sn;
  const float o1 = x.x * sn + x.y * cs;
  const unsigned pk = (unsigned)f2bf(o0) | ((unsigned)f2bf(o1) << 16);
  *(unsigned*)&kb[((size_t)(b * NKV + kh) * SLEN + s) * HD + 2 * j] = pk;
}

// V transpose + cast: qkv v-part -> vt[b][kh][d][s] bf16 (64x64 LDS tiles)
__global__ __launch_bounds__(256) void vcast_kernel(const float* __restrict__ qkv,
                                                    unsigned short* __restrict__ vt) {
  __shared__ float tile[64][65];
  const int tid = threadIdx.x;
  const int bi = blockIdx.x;  // 512 blocks: (b, kh, stile)
  const int st = bi & 31;
  const int kh = (bi >> 5) & 7;
  const int b = bi >> 8;
  const int r = tid >> 2;
  const int c0 = (tid & 3) * 16;
  const float* src = &qkv[(size_t)(b * SLEN + st * 64 + r) * QKVN + NH * HD + NKV * HD + kh * HD + c0];
#pragma unroll
  for (int i = 0; i < 16; i += 4) {
    const float4 v = *(const float4*)(src + i);
    tile[r][c0 + i] = v.x; tile[r][c0 + i + 1] = v.y;
    tile[r][c0 + i + 2] = v.z; tile[r][c0 + i + 3] = v.w;
  }
  __syncthreads();
  alignas(16) unsigned short tmp[16];
#pragma unroll
  for (int i = 0; i < 16; ++i) tmp[i] = f2bf(tile[c0 + i][r]);
  unsigned short* dst = &vt[((size_t)(b * NKV + kh) * HD + r) * SLEN + st * 64 + c0];
  *(bf16x8*)dst = *(bf16x8*)tmp;
  *(bf16x8*)(dst + 8) = *(bf16x8*)(tmp + 8);
}

// ---------------------------------------------------------------------------
// Flash attention, swapped-operand in-register softmax. 1-D grid of 2048 with
// XCD-aware remap: XCD x handles bh in [8x, 8x+8) (K/V+Q fits its 4MB L2).
// Epilogue writes bf16 (feeds bf16 out-proj GEMM).
// ---------------------------------------------------------------------------
__global__ __launch_bounds__(256) void attn_kernel(
    const unsigned short* __restrict__ qb, const unsigned short* __restrict__ kb,
    const unsigned short* __restrict__ vt, unsigned short* __restrict__ aob) {
  __shared__ unsigned short Kl[64][72];       // [key][hd]
  __shared__ unsigned short Vl[64][72];       // [hd][key]  (V^T)
  __shared__ unsigned short Pq[4][16][72];    // per-wave P[q][key]

  const int tid = threadIdx.x;
  const int lane = tid & 63;
  const int wid = tid >> 6;
  const int g = lane >> 4;     // 0..3
  const int fr = lane & 15;    // this lane's q row (within wave)

  const int jb = blockIdx.x;        // 0..2047
  const int slot = jb >> 3;
  const int bh = (jb & 7) * 8 + (slot & 7);
  const int qt = slot >> 3;
  const int b = bh >> 5, h = bh & 31;
  const int kh = h >> 2;
  const size_t qbase = (size_t)bh * SLEN * HD;
  const size_t kbase = (size_t)(b * NKV + kh) * SLEN * HD;
  const size_t vbase = (size_t)(b * NKV + kh) * HD * SLEN;

  const int qrow = qt * 64 + wid * 16 + fr;
  const bf16x8 q0 = *(const bf16x8*)&qb[qbase + (size_t)qrow * HD + g * 8];
  const bf16x8 q1 = *(const bf16x8*)&qb[qbase + (size_t)qrow * HD + 32 + g * 8];

  f32x4 acc[4];   // acc[dt][r] = O^T[dt*16+g*4+r][q=fr]
#pragma unroll
  for (int i = 0; i < 4; i++) acc[i] = (f32x4){0.f, 0.f, 0.f, 0.f};
  float m = -1e30f, l = 0.f;

  const int trow = tid >> 2;        // 0..63
  const int tcol = (tid & 3) * 16;  // 0,16,32,48

  for (int kt = 0; kt < SLEN / 64; ++kt) {
    __syncthreads();
    {
      const int key = kt * 64 + trow;
      *(bf16x8*)&Kl[trow][tcol] = *(const bf16x8*)&kb[kbase + (size_t)key * HD + tcol];
      *(bf16x8*)&Kl[trow][tcol + 8] = *(const bf16x8*)&kb[kbase + (size_t)key * HD + tcol + 8];
      *(bf16x8*)&Vl[trow][tcol] = *(const bf16x8*)&vt[vbase + (size_t)trow * SLEN + kt * 64 + tcol];
      *(bf16x8*)&Vl[trow][tcol + 8] = *(const bf16x8*)&vt[vbase + (size_t)trow * SLEN + kt * 64 + tcol + 8];
    }
    __syncthreads();

    // ---- QK^T (swapped): per lane 16 scores for q=fr, keys j*16+g*4+r ----
    f32x4 sc[4];
#pragma unroll
    for (int j = 0; j < 4; j++) {
      const bf16x8 k0 = *(const bf16x8*)&Kl[j * 16 + fr][g * 8];
      const bf16x8 k1 = *(const bf16x8*)&Kl[j * 16 + fr][32 + g * 8];
      f32x4 s = (f32x4){0.f, 0.f, 0.f, 0.f};
      s = __builtin_amdgcn_mfma_f32_16x16x32_bf16(k0, q0, s, 0, 0, 0);
      s = __builtin_amdgcn_mfma_f32_16x16x32_bf16(k1, q1, s, 0, 0, 0);
      sc[j] = s;
    }

    // ---- in-register online softmax (exp2 domain) ----
    float t01 = fmaxf(fmaxf(sc[0][0], sc[0][1]), fmaxf(sc[0][2], sc[0][3]));
    float t23 = fmaxf(fmaxf(sc[1][0], sc[1][1]), fmaxf(sc[1][2], sc[1][3]));
    float t45 = fmaxf(fmaxf(sc[2][0], sc[2][1]), fmaxf(sc[2][2], sc[2][3]));
    float t67 = fmaxf(fmaxf(sc[3][0], sc[3][1]), fmaxf(sc[3][2], sc[3][3]));
    float tmax = fmaxf(fmaxf(t01, t23), fmaxf(t45, t67));
    tmax = fmaxf(tmax, __shfl_xor(tmax, 16));
    tmax = fmaxf(tmax, __shfl_xor(tmax, 32));

    if (__any(tmax > m + 8.0f)) {   // defer-max: rescale only on real growth
      const float mn = fmaxf(m, tmax);
      const float corr = fast_exp2(m - mn);
      l *= corr;
#pragma unroll
      for (int dt = 0; dt < 4; ++dt) acc[dt] *= corr;
      m = mn;
    }

    float p[4][4];
    float lsum = 0.f;
#pragma unroll
    for (int j = 0; j < 4; j++)
#pragma unroll
      for (int r = 0; r < 4; r++) {
        p[j][r] = fast_exp2(sc[j][r] - m);
        lsum += p[j][r];
      }
    lsum += __shfl_xor(lsum, 16);
    lsum += __shfl_xor(lsum, 32);
    l += lsum;

    // ---- pack P -> bf16, stage per-wave P[q][key] (no barrier needed) ----
#pragma unroll
    for (int j = 0; j < 4; j++) {
      *(unsigned*)&Pq[wid][fr][j * 16 + g * 4] = cvt_pk_bf16(p[j][0], p[j][1]);
      *(unsigned*)&Pq[wid][fr][j * 16 + g * 4 + 2] = cvt_pk_bf16(p[j][2], p[j][3]);
    }

    const bf16x8 pt0 = *(const bf16x8*)&Pq[wid][fr][g * 8];        // keys g*8..+7
    const bf16x8 pt1 = *(const bf16x8*)&Pq[wid][fr][32 + g * 8];   // keys 32+g*8..

    // ---- PV: O^T += V^T · P^T ----
#pragma unroll
    for (int dt = 0; dt < 4; ++dt) {
      const bf16x8 v0 = *(const bf16x8*)&Vl[dt * 16 + fr][g * 8];
      const bf16x8 v1 = *(const bf16x8*)&Vl[dt * 16 + fr][32 + g * 8];
      acc[dt] = __builtin_amdgcn_mfma_f32_16x16x32_bf16(v0, pt0, acc[dt], 0, 0, 0);
      acc[dt] = __builtin_amdgcn_mfma_f32_16x16x32_bf16(v1, pt1, acc[dt], 0, 0, 0);
    }
  }

  const float rl = 1.0f / l;
#pragma unroll
  for (int dt = 0; dt < 4; ++dt) {
    uint2 o;
    o.x = cvt_pk_bf16(acc[dt][0] * rl, acc[dt][1] * rl);
    o.y = cvt_pk_bf16(acc[dt][2] * rl, acc[dt][3] * rl);
    *(uint2*)&aob[(size_t)(b * SLEN + qrow) * DMODEL + h * HD + dt * 16 + g * 4] = o;
  }
}

// ---------------------------------------------------------------------------
extern "C" void kernel_launch(void* const* d_in, const int* in_sizes, int n_in,
                              void* d_out, int out_size, void* d_ws, size_t ws_size,
                              hipStream_t stream) {
  const float* x  = (const float*)d_in[0];
  const float* Wq = (const float*)d_in[1];
  const float* Wk = (const float*)d_in[2];
  const float* Wv = (const float*)d_in[3];
  const float* Wo = (const float*)d_in[4];
  float* out = (float*)d_out;

  char* ws = (char*)d_ws;
  float* qkv = (float*)ws;                  ws += (size_t)MROWS * QKVN * 4;              // 50.3 MB
  unsigned short* qb = (unsigned short*)ws; ws += (size_t)BATCH * NH * SLEN * HD * 2;    // 16.8 MB
  unsigned short* kb = (unsigned short*)ws; ws += (size_t)BATCH * NKV * SLEN * HD * 2;   //  4.2 MB
  unsigned short* vt = (unsigned short*)ws; ws += (size_t)BATCH * NKV * HD * SLEN * 2;   //  4.2 MB
  // region R (aliased, phase 1 -> phase 2):
  unsigned short* xb     = (unsigned short*)ws;                  // 16.8 MB (dead after QKV GEMM)
  unsigned short* aob    = (unsigned short*)ws;                  // aliases xb
  unsigned short* wqkvb  = (unsigned short*)(ws + (size_t)MROWS * DMODEL * 2);  // 12.6 MB
  unsigned short* wob    = wqkvb;                                // aliases wqkvb (dead after QKV GEMM)

  dim3 blk(256);

  // ---- phase 1: bf16 conversions + fused QKV projection ----
  cvt_kernel<<<(MROWS * DMODEL / 8 + 255) / 256, blk, 0, stream>>>(x, xb, MROWS * DMODEL / 8);
  cvt_kernel<<<(NH * HD * DMODEL / 8 + 255) / 256, blk, 0, stream>>>(Wq, wqkvb, NH * HD * DMODEL / 8);
  cvt_kernel<<<(NKV * HD * DMODEL / 8 + 255) / 256, blk, 0, stream>>>(
      Wk, wqkvb + (size_t)NH * HD * DMODEL, NKV * HD * DMODEL / 8);
  cvt_kernel<<<(NKV * HD * DMODEL / 8 + 255) / 256, blk, 0, stream>>>(
      Wv, wqkvb + (size_t)(NH + NKV) * HD * DMODEL, NKV * HD * DMODEL / 8);

  gemm_bf16_kernel<<<dim3(MROWS / 128, QKVN / 128), blk, 0, stream>>>(
      xb, wqkvb, qkv, MROWS, QKVN, DMODEL);

  // ---- phase 2: RoPE / layouts; Wo conversion (wqkvb now dead) ----
  rope_q_kernel<<<(BATCH * NH * SLEN * 32) / 256, blk, 0, stream>>>(qkv, qb);
  rope_k_kernel<<<(BATCH * NKV * SLEN * 32) / 256, blk, 0, stream>>>(qkv, kb);
  vcast_kernel<<<BATCH * NKV * (SLEN / 64), blk, 0, stream>>>(qkv, vt);
  cvt_kernel<<<(DMODEL * DMODEL / 8 + 255) / 256, blk, 0, stream>>>(Wo, wob, DMODEL * DMODEL / 8);

  // ---- attention (writes bf16 aob; xb dead) ----
  attn_kernel<<<dim3(2048), blk, 0, stream>>>(qb, kb, vt, aob);

  // ---- output projection (plain bf16) ----
  gemm_bf16_kernel<<<dim3(MROWS / 128, DMODEL / 128), blk, 0, stream>>>(
      aob, wob, out, MROWS, DMODEL, DMODEL);
}

// Round 4
// 264.729 us; speedup vs baseline: 2.0077x; 1.1355x over previous
//
#include <hip/hip_runtime.h>
#include <hip/hip_bf16.h>
#include <math.h>

#define SLEN 2048
#define DMODEL 2048
#define NH 32
#define NKV 8
#define HD 64
#define BATCH 2
#define MROWS (BATCH * SLEN)            // 4096
#define QKVN (NH * HD + 2 * NKV * HD)   // 3072

typedef __attribute__((ext_vector_type(8))) short bf16x8;
typedef __attribute__((ext_vector_type(4))) float f32x4;
typedef __attribute__((ext_vector_type(16))) float f32x16;
typedef __attribute__((ext_vector_type(4))) unsigned u32x4;

__device__ __forceinline__ unsigned short f2bf(float f) {
  union { float f; unsigned u; } v; v.f = f;
  return (unsigned short)((v.u + 0x7FFFu + ((v.u >> 16) & 1u)) >> 16);
}
__device__ __forceinline__ unsigned cvt_pk_bf16(float lo, float hi) {
  unsigned r;
  asm("v_cvt_pk_bf16_f32 %0, %1, %2" : "=v"(r) : "v"(lo), "v"(hi));
  return r;
}
__device__ __forceinline__ float fast_exp2(float x) {
#if __has_builtin(__builtin_amdgcn_exp2f)
  return __builtin_amdgcn_exp2f(x);
#else
  return exp2f(x);
#endif
}
// async global->LDS, 16B per lane: lane l writes lds_base + l*16
__device__ __forceinline__ void gload_lds16(const unsigned short* g, unsigned short* l) {
  __builtin_amdgcn_global_load_lds(
      (const __attribute__((address_space(1))) unsigned int*)(g),
      (__attribute__((address_space(3))) unsigned int*)(l), 16, 0, 0);
}

// ---------------------------------------------------------------------------
// fp32 -> bf16 streaming convert (8 elems/thread)
// ---------------------------------------------------------------------------
__global__ __launch_bounds__(256) void cvt_kernel(const float* __restrict__ src,
                                                  unsigned short* __restrict__ dst,
                                                  int n8) {
  const int i = blockIdx.x * 256 + threadIdx.x;
  if (i >= n8) return;
  const float4 a = *(const float4*)&src[(size_t)i * 8];
  const float4 b = *(const float4*)&src[(size_t)i * 8 + 4];
  uint4 o;
  o.x = cvt_pk_bf16(a.x, a.y);
  o.y = cvt_pk_bf16(a.z, a.w);
  o.z = cvt_pk_bf16(b.x, b.y);
  o.w = cvt_pk_bf16(b.z, b.w);
  *(uint4*)&dst[(size_t)i * 8] = o;
}

// ---------------------------------------------------------------------------
// bf16 GEMM (m97 structure): C[m,n] = sum_k A[m,k]*B[n,k], fp32 out.
// 128x128 tile, BK=32, 4 waves (2x2), global_load_lds(16) staging, 2-barrier.
// ---------------------------------------------------------------------------
__global__ __launch_bounds__(256) void gemm_bf16_kernel(
    const unsigned short* __restrict__ A, const unsigned short* __restrict__ B,
    float* __restrict__ C, int M, int N, int K) {
  __shared__ unsigned short As[128][32];
  __shared__ unsigned short Bs[128][32];

  const int tid = threadIdx.x;
  const int lane = tid & 63;
  const int wid = tid >> 6;
  const int g = lane >> 4;
  const int fr = lane & 15;
  const int m0 = blockIdx.x * 128;
  const int n0 = blockIdx.y * 128;
  const int wm = (wid >> 1) * 64;
  const int wn = (wid & 1) * 64;

  const int srow = wid * 32 + (lane >> 2);
  const int scol = (lane & 3) * 8;
  const unsigned short* ga = &A[(size_t)(m0 + srow) * K + scol];
  const unsigned short* gb = &B[(size_t)(n0 + srow) * K + scol];
  unsigned short* la0 = &As[wid * 32][0];
  unsigned short* la1 = &As[wid * 32 + 16][0];
  unsigned short* lb0 = &Bs[wid * 32][0];
  unsigned short* lb1 = &Bs[wid * 32 + 16][0];
  const size_t rstep = (size_t)16 * K;

  f32x4 acc[4][4];
#pragma unroll
  for (int i = 0; i < 4; i++)
#pragma unroll
    for (int j = 0; j < 4; j++) acc[i][j] = (f32x4){0.f, 0.f, 0.f, 0.f};

  for (int kt = 0; kt < K; kt += 32) {
    __syncthreads();
    gload_lds16(ga + kt, la0);
    gload_lds16(ga + kt + rstep, la1);
    gload_lds16(gb + kt, lb0);
    gload_lds16(gb + kt + rstep, lb1);
    __syncthreads();

    bf16x8 af[4], bfr[4];
#pragma unroll
    for (int i = 0; i < 4; i++) {
      af[i] = *(const bf16x8*)&As[wm + i * 16 + fr][g * 8];
      bfr[i] = *(const bf16x8*)&Bs[wn + i * 16 + fr][g * 8];
    }
#pragma unroll
    for (int i = 0; i < 4; i++)
#pragma unroll
      for (int j = 0; j < 4; j++)
        acc[i][j] = __builtin_amdgcn_mfma_f32_16x16x32_bf16(af[i], bfr[j], acc[i][j], 0, 0, 0);
  }

#pragma unroll
  for (int i = 0; i < 4; i++)
#pragma unroll
    for (int j = 0; j < 4; j++)
#pragma unroll
      for (int r = 0; r < 4; r++)
        C[(size_t)(m0 + wm + i * 16 + g * 4 + r) * N + n0 + wn + j * 16 + fr] = acc[i][j][r];
}

// ---------------------------------------------------------------------------
// RoPE + cast for Q: qkv[.., h*64+d] -> qb[b][h][s][d] bf16.
// Scale (1/8)*log2(e) folded so attention softmax runs in exp2 domain.
// ---------------------------------------------------------------------------
__global__ __launch_bounds__(256) void rope_q_kernel(const float* __restrict__ qkv,
                                                     unsigned short* __restrict__ qb) {
  const int idx = blockIdx.x * 256 + threadIdx.x;  // 2^22 total
  const int j = idx & 31;
  const int s = (idx >> 5) & (SLEN - 1);
  const int h = (idx >> 16) & (NH - 1);
  const int b = idx >> 21;
  const float2 x = *(const float2*)&qkv[(size_t)(b * SLEN + s) * QKVN + h * HD + 2 * j];
  const float inv = expf(-0.14391156831f * (float)(2 * j));  // ln(1e4)/64
  const float ang = (float)s * inv;
  float sn, cs;
  sincosf(ang, &sn, &cs);
  const float SC = 0.18033688011f;  // 0.125 * log2(e)
  const float o0 = (x.x * cs - x.y * sn) * SC;
  const float o1 = (x.x * sn + x.y * cs) * SC;
  const unsigned pk = (unsigned)f2bf(o0) | ((unsigned)f2bf(o1) << 16);
  *(unsigned*)&qb[((size_t)(b * NH + h) * SLEN + s) * HD + 2 * j] = pk;
}

// RoPE + cast for K: -> kb[b][kh][s][d] bf16 (no scale)
__global__ __launch_bounds__(256) void rope_k_kernel(const float* __restrict__ qkv,
                                                     unsigned short* __restrict__ kb) {
  const int idx = blockIdx.x * 256 + threadIdx.x;  // 2^20 total
  const int j = idx & 31;
  const int s = (idx >> 5) & (SLEN - 1);
  const int kh = (idx >> 16) & (NKV - 1);
  const int b = idx >> 19;
  const float2 x = *(const float2*)&qkv[(size_t)(b * SLEN + s) * QKVN + NH * HD + kh * HD + 2 * j];
  const float inv = expf(-0.14391156831f * (float)(2 * j));
  const float ang = (float)s * inv;
  float sn, cs;
  sincosf(ang, &sn, &cs);
  const float o0 = x.x * cs - x.y * sn;
  const float o1 = x.x * sn + x.y * cs;
  const unsigned pk = (unsigned)f2bf(o0) | ((unsigned)f2bf(o1) << 16);
  *(unsigned*)&kb[((size_t)(b * NKV + kh) * SLEN + s) * HD + 2 * j] = pk;
}

// V transpose + cast: qkv v-part -> vt[b][kh][d][s] bf16 (64x64 LDS tiles)
__global__ __launch_bounds__(256) void vcast_kernel(const float* __restrict__ qkv,
                                                    unsigned short* __restrict__ vt) {
  __shared__ float tile[64][65];
  const int tid = threadIdx.x;
  const int bi = blockIdx.x;  // 512 blocks: (b, kh, stile)
  const int st = bi & 31;
  const int kh = (bi >> 5) & 7;
  const int b = bi >> 8;
  const int r = tid >> 2;
  const int c0 = (tid & 3) * 16;
  const float* src = &qkv[(size_t)(b * SLEN + st * 64 + r) * QKVN + NH * HD + NKV * HD + kh * HD + c0];
#pragma unroll
  for (int i = 0; i < 16; i += 4) {
    const float4 v = *(const float4*)(src + i);
    tile[r][c0 + i] = v.x; tile[r][c0 + i + 1] = v.y;
    tile[r][c0 + i + 2] = v.z; tile[r][c0 + i + 3] = v.w;
  }
  __syncthreads();
  alignas(16) unsigned short tmp[16];
#pragma unroll
  for (int i = 0; i < 16; ++i) tmp[i] = f2bf(tile[c0 + i][r]);
  unsigned short* dst = &vt[((size_t)(b * NKV + kh) * HD + r) * SLEN + st * 64 + c0];
  *(bf16x8*)dst = *(bf16x8*)tmp;
  *(bf16x8*)(dst + 8) = *(bf16x8*)(tmp + 8);
}

// ---------------------------------------------------------------------------
// Flash attention, 32x32 MFMA, fully in-register softmax + P (no P LDS).
// Grid 1024 (16 q-blocks x 64 bh, XCD-remapped). 4 waves x 32 q-rows.
// QK^T: sc = mfma32(K, Q) -> C[key][q]; lane: q = lane&31, 16 keys/tile.
// P->B-frag via cvt_pk_bf16 + v_permlane32_swap (lanes l, l+32 hold
// complementary key halves of the same q).
// K/V staged via global_load_lds, XOR-swizzled (source-side), dbuf,
// one barrier per 64-key tile, stage of t+1 in flight during compute of t.
// ---------------------------------------------------------------------------
__global__ __launch_bounds__(256) void attn_kernel(
    const unsigned short* __restrict__ qb, const unsigned short* __restrict__ kb,
    const unsigned short* __restrict__ vt, unsigned short* __restrict__ aob) {
  __shared__ unsigned short Kbuf[2][4096];   // [key 64][hd 64], row-swizzled
  __shared__ unsigned short Vbuf[2][4096];   // [d 64][key 64], row-swizzled

  const int tid = threadIdx.x;
  const int lane = tid & 63;
  const int wid = tid >> 6;
  const int lq = lane & 31;      // q column (and key/d row for frag reads)
  const int hi = lane >> 5;
  const int sw = lane & 7;       // row&7 for swizzle

  const int jb = blockIdx.x;     // 1024 blocks
  const int xcd = jb & 7;
  const int idx = jb >> 3;       // 0..127
  const int bh = xcd * 8 + (idx & 7);
  const int qt = idx >> 3;       // 0..15
  const int b = bh >> 5, h = bh & 31;
  const int kh = h >> 2;
  const size_t qbase = (size_t)bh * SLEN * HD;
  const size_t kbase = (size_t)(b * NKV + kh) * SLEN * HD;
  const size_t vbase = (size_t)(b * NKV + kh) * HD * SLEN;

  // Q fragments hoisted to registers: B[k=hd][col=q]
  const int q0 = qt * 128 + wid * 32;
  bf16x8 qf[4];
#pragma unroll
  for (int ks = 0; ks < 4; ++ks)
    qf[ks] = *(const bf16x8*)&qb[qbase + (size_t)(q0 + lq) * HD + ks * 16 + hi * 8];

  // staging: wave wid stages chunks {2*wid, 2*wid+1} of K and V (1KB each).
  // source pre-swizzled: chunk-col = (l&7) ^ ((l>>3)&7)  (row&7 == (l>>3)&7).
  const int ci0 = wid * 2;
  const int swzc = ((lane & 7) ^ ((lane >> 3) & 7)) * 8;
  const int srow = ci0 * 8 + (lane >> 3);
  const unsigned short* gk0 = kb + kbase + (size_t)srow * HD + swzc;
  const unsigned short* gk1 = gk0 + (size_t)8 * HD;
  const unsigned short* gv0 = vt + vbase + (size_t)srow * SLEN + swzc;
  const unsigned short* gv1 = gv0 + (size_t)8 * SLEN;

  f32x16 acc0 = {}, acc1 = {};
  float m = -1e30f, l = 0.f;

  // prologue: stage tile 0 into buffer 0
  gload_lds16(gk0, &Kbuf[0][ci0 * 512]);
  gload_lds16(gk1, &Kbuf[0][ci0 * 512 + 512]);
  gload_lds16(gv0, &Vbuf[0][ci0 * 512]);
  gload_lds16(gv1, &Vbuf[0][ci0 * 512 + 512]);

  for (int kt = 0; kt < SLEN / 64; ++kt) {
    const int cur = kt & 1;
    asm volatile("s_waitcnt vmcnt(0)" ::: "memory");
    __syncthreads();
    if (kt + 1 < SLEN / 64) {
      const int nxt = cur ^ 1;
      const size_t ko = (size_t)(kt + 1) * 64 * HD;
      const size_t vo = (size_t)(kt + 1) * 64;
      gload_lds16(gk0 + ko, &Kbuf[nxt][ci0 * 512]);
      gload_lds16(gk1 + ko, &Kbuf[nxt][ci0 * 512 + 512]);
      gload_lds16(gv0 + vo, &Vbuf[nxt][ci0 * 512]);
      gload_lds16(gv1 + vo, &Vbuf[nxt][ci0 * 512 + 512]);
    }

    // ---- QK^T: C[key][q], two 32-key subtiles ----
    f32x16 s0 = {}, s1 = {};
#pragma unroll
    for (int ks = 0; ks < 4; ++ks) {
      const bf16x8 kf = *(const bf16x8*)&Kbuf[cur][lq * HD + (((ks * 2 + hi) ^ sw) * 8)];
      s0 = __builtin_amdgcn_mfma_f32_32x32x16_bf16(kf, qf[ks], s0, 0, 0, 0);
    }
#pragma unroll
    for (int ks = 0; ks < 4; ++ks) {
      const bf16x8 kf = *(const bf16x8*)&Kbuf[cur][(32 + lq) * HD + (((ks * 2 + hi) ^ sw) * 8)];
      s1 = __builtin_amdgcn_mfma_f32_32x32x16_bf16(kf, qf[ks], s1, 0, 0, 0);
    }

    // ---- online softmax (exp2 domain), in-register ----
    float tm = s0[0];
#pragma unroll
    for (int i = 1; i < 16; ++i) tm = fmaxf(tm, s0[i]);
#pragma unroll
    for (int i = 0; i < 16; ++i) tm = fmaxf(tm, s1[i]);
    tm = fmaxf(tm, __shfl_xor(tm, 32));

    if (__any(tm > m + 8.0f)) {  // defer-max
      const float mn = fmaxf(m, tm);
      const float corr = fast_exp2(m - mn);
      l *= corr;
#pragma unroll
      for (int i = 0; i < 16; ++i) { acc0[i] *= corr; acc1[i] *= corr; }
      m = mn;
    }

    float p0[16], p1[16];
    float lsum = 0.f;
#pragma unroll
    for (int i = 0; i < 16; ++i) { p0[i] = fast_exp2(s0[i] - m); lsum += p0[i]; }
#pragma unroll
    for (int i = 0; i < 16; ++i) { p1[i] = fast_exp2(s1[i] - m); lsum += p1[i]; }
    lsum += __shfl_xor(lsum, 32);
    l += lsum;

    // ---- P -> bf16 B-frags via cvt_pk + permlane32_swap (no LDS) ----
    unsigned u0[8], u1[8];
#pragma unroll
    for (int c = 0; c < 4; ++c) {
      u0[2 * c] = cvt_pk_bf16(p0[4 * c], p0[4 * c + 1]);
      u0[2 * c + 1] = cvt_pk_bf16(p0[4 * c + 2], p0[4 * c + 3]);
      u1[2 * c] = cvt_pk_bf16(p1[4 * c], p1[4 * c + 1]);
      u1[2 * c + 1] = cvt_pk_bf16(p1[4 * c + 2], p1[4 * c + 3]);
    }
    bf16x8 pf[4];
    {
      unsigned a0 = u0[0], b0 = u0[2];
      asm volatile("v_permlane32_swap_b32 %0, %1" : "+v"(a0), "+v"(b0));
      unsigned a1 = u0[1], b1 = u0[3];
      asm volatile("v_permlane32_swap_b32 %0, %1" : "+v"(a1), "+v"(b1));
      u32x4 t = {a0, a1, b0, b1};
      pf[0] = __builtin_bit_cast(bf16x8, t);
      unsigned a2 = u0[4], b2 = u0[6];
      asm volatile("v_permlane32_swap_b32 %0, %1" : "+v"(a2), "+v"(b2));
      unsigned a3 = u0[5], b3 = u0[7];
      asm volatile("v_permlane32_swap_b32 %0, %1" : "+v"(a3), "+v"(b3));
      u32x4 t2 = {a2, a3, b2, b3};
      pf[1] = __builtin_bit_cast(bf16x8, t2);
      unsigned a4 = u1[0], b4 = u1[2];
      asm volatile("v_permlane32_swap_b32 %0, %1" : "+v"(a4), "+v"(b4));
      unsigned a5 = u1[1], b5 = u1[3];
      asm volatile("v_permlane32_swap_b32 %0, %1" : "+v"(a5), "+v"(b5));
      u32x4 t3 = {a4, a5, b4, b5};
      pf[2] = __builtin_bit_cast(bf16x8, t3);
      unsigned a6 = u1[4], b6 = u1[6];
      asm volatile("v_permlane32_swap_b32 %0, %1" : "+v"(a6), "+v"(b6));
      unsigned a7 = u1[5], b7 = u1[7];
      asm volatile("v_permlane32_swap_b32 %0, %1" : "+v"(a7), "+v"(b7));
      u32x4 t4 = {a6, a7, b6, b7};
      pf[3] = __builtin_bit_cast(bf16x8, t4);
    }

    // ---- PV: O^T[d][q] += V^T . P^T ----
#pragma unroll
    for (int ks = 0; ks < 4; ++ks) {
      const bf16x8 vf = *(const bf16x8*)&Vbuf[cur][lq * 64 + (((ks * 2 + hi) ^ sw) * 8)];
      acc0 = __builtin_amdgcn_mfma_f32_32x32x16_bf16(vf, pf[ks], acc0, 0, 0, 0);
    }
#pragma unroll
    for (int ks = 0; ks < 4; ++ks) {
      const bf16x8 vf = *(const bf16x8*)&Vbuf[cur][(32 + lq) * 64 + (((ks * 2 + hi) ^ sw) * 8)];
      acc1 = __builtin_amdgcn_mfma_f32_32x32x16_bf16(vf, pf[ks], acc1, 0, 0, 0);
    }
  }

  // ---- epilogue: d = dsub*32 + 8c + 4hi + (0..3), q = q0 + lq ----
  const float rl = 1.0f / l;
  const size_t obase = (size_t)(b * SLEN + q0 + lq) * DMODEL + h * HD;
#pragma unroll
  for (int c = 0; c < 4; ++c) {
    uint2 o;
    o.x = cvt_pk_bf16(acc0[4 * c] * rl, acc0[4 * c + 1] * rl);
    o.y = cvt_pk_bf16(acc0[4 * c + 2] * rl, acc0[4 * c + 3] * rl);
    *(uint2*)&aob[obase + 8 * c + 4 * hi] = o;
    uint2 o2;
    o2.x = cvt_pk_bf16(acc1[4 * c] * rl, acc1[4 * c + 1] * rl);
    o2.y = cvt_pk_bf16(acc1[4 * c + 2] * rl, acc1[4 * c + 3] * rl);
    *(uint2*)&aob[obase + 32 + 8 * c + 4 * hi] = o2;
  }
}

// ---------------------------------------------------------------------------
extern "C" void kernel_launch(void* const* d_in, const int* in_sizes, int n_in,
                              void* d_out, int out_size, void* d_ws, size_t ws_size,
                              hipStream_t stream) {
  const float* x  = (const float*)d_in[0];
  const float* Wq = (const float*)d_in[1];
  const float* Wk = (const float*)d_in[2];
  const float* Wv = (const float*)d_in[3];
  const float* Wo = (const float*)d_in[4];
  float* out = (float*)d_out;

  char* ws = (char*)d_ws;
  float* qkv = (float*)ws;                  ws += (size_t)MROWS * QKVN * 4;              // 50.3 MB
  unsigned short* qb = (unsigned short*)ws; ws += (size_t)BATCH * NH * SLEN * HD * 2;    // 16.8 MB
  unsigned short* kb = (unsigned short*)ws; ws += (size_t)BATCH * NKV * SLEN * HD * 2;   //  4.2 MB
  unsigned short* vt = (unsigned short*)ws; ws += (size_t)BATCH * NKV * HD * SLEN * 2;   //  4.2 MB
  // region R (aliased, phase 1 -> phase 2):
  unsigned short* xb     = (unsigned short*)ws;                  // 16.8 MB (dead after QKV GEMM)
  unsigned short* aob    = (unsigned short*)ws;                  // aliases xb
  unsigned short* wqkvb  = (unsigned short*)(ws + (size_t)MROWS * DMODEL * 2);  // 12.6 MB
  unsigned short* wob    = wqkvb;                                // aliases wqkvb (dead after QKV GEMM)

  dim3 blk(256);

  // ---- phase 1: bf16 conversions + fused QKV projection ----
  cvt_kernel<<<(MROWS * DMODEL / 8 + 255) / 256, blk, 0, stream>>>(x, xb, MROWS * DMODEL / 8);
  cvt_kernel<<<(NH * HD * DMODEL / 8 + 255) / 256, blk, 0, stream>>>(Wq, wqkvb, NH * HD * DMODEL / 8);
  cvt_kernel<<<(NKV * HD * DMODEL / 8 + 255) / 256, blk, 0, stream>>>(
      Wk, wqkvb + (size_t)NH * HD * DMODEL, NKV * HD * DMODEL / 8);
  cvt_kernel<<<(NKV * HD * DMODEL / 8 + 255) / 256, blk, 0, stream>>>(
      Wv, wqkvb + (size_t)(NH + NKV) * HD * DMODEL, NKV * HD * DMODEL / 8);

  gemm_bf16_kernel<<<dim3(MROWS / 128, QKVN / 128), blk, 0, stream>>>(
      xb, wqkvb, qkv, MROWS, QKVN, DMODEL);

  // ---- phase 2: RoPE / layouts; Wo conversion (wqkvb now dead) ----
  rope_q_kernel<<<(BATCH * NH * SLEN * 32) / 256, blk, 0, stream>>>(qkv, qb);
  rope_k_kernel<<<(BATCH * NKV * SLEN * 32) / 256, blk, 0, stream>>>(qkv, kb);
  vcast_kernel<<<BATCH * NKV * (SLEN / 64), blk, 0, stream>>>(qkv, vt);
  cvt_kernel<<<(DMODEL * DMODEL / 8 + 255) / 256, blk, 0, stream>>>(Wo, wob, DMODEL * DMODEL / 8);

  // ---- attention (writes bf16 aob; xb dead) ----
  attn_kernel<<<dim3(1024), blk, 0, stream>>>(qb, kb, vt, aob);

  // ---- output projection (plain bf16) ----
  gemm_bf16_kernel<<<dim3(MROWS / 128, DMODEL / 128), blk, 0, stream>>>(
      aob, wob, out, MROWS, DMODEL, DMODEL);
}

// Round 6
// 252.444 us; speedup vs baseline: 2.1054x; 1.0487x over previous
//
#include <hip/hip_runtime.h>
#include <hip/hip_bf16.h>
#include <math.h>

#define SLEN 2048
#define DMODEL 2048
#define NH 32
#define NKV 8
#define HD 64
#define BATCH 2
#define MROWS (BATCH * SLEN)            // 4096
#define QKVN (NH * HD + 2 * NKV * HD)   // 3072

typedef __attribute__((ext_vector_type(8))) short bf16x8;
typedef __attribute__((ext_vector_type(4))) float f32x4;
typedef __attribute__((ext_vector_type(16))) float f32x16;
typedef __attribute__((ext_vector_type(4))) unsigned u32x4;

__device__ __forceinline__ unsigned short f2bf(float f) {
  union { float f; unsigned u; } v; v.f = f;
  return (unsigned short)((v.u + 0x7FFFu + ((v.u >> 16) & 1u)) >> 16);
}
__device__ __forceinline__ float bf2f(unsigned short h) {
  union { unsigned u; float f; } v; v.u = ((unsigned)h) << 16;
  return v.f;
}
__device__ __forceinline__ unsigned cvt_pk_bf16(float lo, float hi) {
  unsigned r;
  asm("v_cvt_pk_bf16_f32 %0, %1, %2" : "=v"(r) : "v"(lo), "v"(hi));
  return r;
}
__device__ __forceinline__ float fast_exp2(float x) {
#if __has_builtin(__builtin_amdgcn_exp2f)
  return __builtin_amdgcn_exp2f(x);
#else
  return exp2f(x);
#endif
}
// async global->LDS, 16B per lane: lane l writes lds_base + l*16
__device__ __forceinline__ void gload_lds16(const unsigned short* g, unsigned short* l) {
  __builtin_amdgcn_global_load_lds(
      (const __attribute__((address_space(1))) unsigned int*)(g),
      (__attribute__((address_space(3))) unsigned int*)(l), 16, 0, 0);
}

// ---------------------------------------------------------------------------
// fp32 -> bf16 streaming convert (8 elems/thread)
// ---------------------------------------------------------------------------
__global__ __launch_bounds__(256) void cvt_kernel(const float* __restrict__ src,
                                                  unsigned short* __restrict__ dst,
                                                  int n8) {
  const int i = blockIdx.x * 256 + threadIdx.x;
  if (i >= n8) return;
  const float4 a = *(const float4*)&src[(size_t)i * 8];
  const float4 b = *(const float4*)&src[(size_t)i * 8 + 4];
  uint4 o;
  o.x = cvt_pk_bf16(a.x, a.y);
  o.y = cvt_pk_bf16(a.z, a.w);
  o.z = cvt_pk_bf16(b.x, b.y);
  o.w = cvt_pk_bf16(b.z, b.w);
  *(uint4*)&dst[(size_t)i * 8] = o;
}

// all four weight matrices in one launch (saves 3 launches)
// vec8 regions: Wq 524288 | Wk 131072 | Wv 131072 | Wo 524288
__global__ __launch_bounds__(256) void cvt_w4_kernel(
    const float* __restrict__ Wq, const float* __restrict__ Wk,
    const float* __restrict__ Wv, const float* __restrict__ Wo,
    unsigned short* __restrict__ wqkvb, unsigned short* __restrict__ wob) {
  const int i = blockIdx.x * 256 + threadIdx.x;  // 0 .. 1310719
  const float* src;
  unsigned short* dst;
  size_t off;
  if (i < 524288)       { src = Wq; dst = wqkvb;           off = i; }
  else if (i < 655360)  { src = Wk; dst = wqkvb + 4194304; off = i - 524288; }
  else if (i < 786432)  { src = Wv; dst = wqkvb + 5242880; off = i - 655360; }
  else                  { src = Wo; dst = wob;             off = i - 786432; }
  const float4 a = *(const float4*)&src[off * 8];
  const float4 b = *(const float4*)&src[off * 8 + 4];
  uint4 o;
  o.x = cvt_pk_bf16(a.x, a.y);
  o.y = cvt_pk_bf16(a.z, a.w);
  o.z = cvt_pk_bf16(b.x, b.y);
  o.w = cvt_pk_bf16(b.z, b.w);
  *(uint4*)&dst[off * 8] = o;
}

// ---------------------------------------------------------------------------
// bf16 GEMM (m97 structure): C[m,n] = sum_k A[m,k]*B[n,k].
// 128x128 tile, BK=32, 4 waves (2x2), global_load_lds(16) staging, 2-barrier.
// OUTBF16: write bf16 instead of fp32.
// ---------------------------------------------------------------------------
template <int OUTBF16>
__global__ __launch_bounds__(256) void gemm_bf16_kernel(
    const unsigned short* __restrict__ A, const unsigned short* __restrict__ B,
    void* __restrict__ Cv, int M, int N, int K) {
  __shared__ unsigned short As[128][32];
  __shared__ unsigned short Bs[128][32];

  const int tid = threadIdx.x;
  const int lane = tid & 63;
  const int wid = tid >> 6;
  const int g = lane >> 4;
  const int fr = lane & 15;
  const int m0 = blockIdx.x * 128;
  const int n0 = blockIdx.y * 128;
  const int wm = (wid >> 1) * 64;
  const int wn = (wid & 1) * 64;

  const int srow = wid * 32 + (lane >> 2);
  const int scol = (lane & 3) * 8;
  const unsigned short* ga = &A[(size_t)(m0 + srow) * K + scol];
  const unsigned short* gb = &B[(size_t)(n0 + srow) * K + scol];
  unsigned short* la0 = &As[wid * 32][0];
  unsigned short* la1 = &As[wid * 32 + 16][0];
  unsigned short* lb0 = &Bs[wid * 32][0];
  unsigned short* lb1 = &Bs[wid * 32 + 16][0];
  const size_t rstep = (size_t)16 * K;

  f32x4 acc[4][4];
#pragma unroll
  for (int i = 0; i < 4; i++)
#pragma unroll
    for (int j = 0; j < 4; j++) acc[i][j] = (f32x4){0.f, 0.f, 0.f, 0.f};

  for (int kt = 0; kt < K; kt += 32) {
    __syncthreads();
    gload_lds16(ga + kt, la0);
    gload_lds16(ga + kt + rstep, la1);
    gload_lds16(gb + kt, lb0);
    gload_lds16(gb + kt + rstep, lb1);
    __syncthreads();

    bf16x8 af[4], bfr[4];
#pragma unroll
    for (int i = 0; i < 4; i++) {
      af[i] = *(const bf16x8*)&As[wm + i * 16 + fr][g * 8];
      bfr[i] = *(const bf16x8*)&Bs[wn + i * 16 + fr][g * 8];
    }
#pragma unroll
    for (int i = 0; i < 4; i++)
#pragma unroll
      for (int j = 0; j < 4; j++)
        acc[i][j] = __builtin_amdgcn_mfma_f32_16x16x32_bf16(af[i], bfr[j], acc[i][j], 0, 0, 0);
  }

  if constexpr (OUTBF16) {
    unsigned short* C = (unsigned short*)Cv;
#pragma unroll
    for (int i = 0; i < 4; i++)
#pragma unroll
      for (int j = 0; j < 4; j++)
#pragma unroll
        for (int r = 0; r < 4; r++)
          C[(size_t)(m0 + wm + i * 16 + g * 4 + r) * N + n0 + wn + j * 16 + fr] =
              f2bf(acc[i][j][r]);
  } else {
    float* C = (float*)Cv;
#pragma unroll
    for (int i = 0; i < 4; i++)
#pragma unroll
      for (int j = 0; j < 4; j++)
#pragma unroll
        for (int r = 0; r < 4; r++)
          C[(size_t)(m0 + wm + i * 16 + g * 4 + r) * N + n0 + wn + j * 16 + fr] =
              acc[i][j][r];
  }
}

// ---------------------------------------------------------------------------
// RoPE on bf16 qkv for Q: -> qb[b][h][s][d] bf16, scale (1/8)*log2(e) folded.
// ---------------------------------------------------------------------------
__global__ __launch_bounds__(256) void rope_q_kernel(const unsigned short* __restrict__ qkvb,
                                                     unsigned short* __restrict__ qb) {
  const int idx = blockIdx.x * 256 + threadIdx.x;  // 2^22 total
  const int j = idx & 31;
  const int s = (idx >> 5) & (SLEN - 1);
  const int h = (idx >> 16) & (NH - 1);
  const int b = idx >> 21;
  const unsigned pin = *(const unsigned*)&qkvb[(size_t)(b * SLEN + s) * QKVN + h * HD + 2 * j];
  const float x0 = bf2f((unsigned short)(pin & 0xffffu));
  const float x1 = bf2f((unsigned short)(pin >> 16));
  const float inv = expf(-0.14391156831f * (float)(2 * j));  // ln(1e4)/64
  const float ang = (float)s * inv;
  float sn, cs;
  sincosf(ang, &sn, &cs);
  const float SC = 0.18033688011f;  // 0.125 * log2(e)
  const float o0 = (x0 * cs - x1 * sn) * SC;
  const float o1 = (x0 * sn + x1 * cs) * SC;
  *(unsigned*)&qb[((size_t)(b * NH + h) * SLEN + s) * HD + 2 * j] = cvt_pk_bf16(o0, o1);
}

// RoPE for K: -> kb[b][kh][s][d] bf16 (no scale)
__global__ __launch_bounds__(256) void rope_k_kernel(const unsigned short* __restrict__ qkvb,
                                                     unsigned short* __restrict__ kb) {
  const int idx = blockIdx.x * 256 + threadIdx.x;  // 2^20 total
  const int j = idx & 31;
  const int s = (idx >> 5) & (SLEN - 1);
  const int kh = (idx >> 16) & (NKV - 1);
  const int b = idx >> 19;
  const unsigned pin =
      *(const unsigned*)&qkvb[(size_t)(b * SLEN + s) * QKVN + NH * HD + kh * HD + 2 * j];
  const float x0 = bf2f((unsigned short)(pin & 0xffffu));
  const float x1 = bf2f((unsigned short)(pin >> 16));
  const float inv = expf(-0.14391156831f * (float)(2 * j));
  const float ang = (float)s * inv;
  float sn, cs;
  sincosf(ang, &sn, &cs);
  const float o0 = x0 * cs - x1 * sn;
  const float o1 = x0 * sn + x1 * cs;
  *(unsigned*)&kb[((size_t)(b * NKV + kh) * SLEN + s) * HD + 2 * j] = cvt_pk_bf16(o0, o1);
}

// V transpose (bf16 -> bf16): qkv v-part -> vt[b][kh][d][s]
__global__ __launch_bounds__(256) void vcast_kernel(const unsigned short* __restrict__ qkvb,
                                                    unsigned short* __restrict__ vt) {
  __shared__ unsigned short tile[64][72];
  const int tid = threadIdx.x;
  const int bi = blockIdx.x;  // 512 blocks: (b, kh, stile)
  const int st = bi & 31;
  const int kh = (bi >> 5) & 7;
  const int b = bi >> 8;
  const int r = tid >> 2;
  const int c0 = (tid & 3) * 16;
  const unsigned short* src =
      &qkvb[(size_t)(b * SLEN + st * 64 + r) * QKVN + (NH + NKV) * HD + kh * HD + c0];
  *(bf16x8*)&tile[r][c0] = *(const bf16x8*)src;
  *(bf16x8*)&tile[r][c0 + 8] = *(const bf16x8*)(src + 8);
  __syncthreads();
  alignas(16) unsigned short tmp[16];
#pragma unroll
  for (int i = 0; i < 16; ++i) tmp[i] = tile[c0 + i][r];
  unsigned short* dst = &vt[((size_t)(b * NKV + kh) * HD + r) * SLEN + st * 64 + c0];
  *(bf16x8*)dst = *(bf16x8*)tmp;
  *(bf16x8*)(dst + 8) = *(bf16x8*)(tmp + 8);
}

// ---------------------------------------------------------------------------
// Flash attention, 32x32 MFMA, fully in-register softmax + P (no P LDS).
// EXACT R4 kernel (proven passing) — R5's attn changes reverted for bisection.
// Grid 1024 (16 q-blocks x 64 bh, XCD-remapped). 4 waves x 32 q-rows.
// ---------------------------------------------------------------------------
__global__ __launch_bounds__(256) void attn_kernel(
    const unsigned short* __restrict__ qb, const unsigned short* __restrict__ kb,
    const unsigned short* __restrict__ vt, unsigned short* __restrict__ aob) {
  __shared__ unsigned short Kbuf[2][4096];   // [key 64][hd 64], row-swizzled
  __shared__ unsigned short Vbuf[2][4096];   // [d 64][key 64], row-swizzled

  const int tid = threadIdx.x;
  const int lane = tid & 63;
  const int wid = tid >> 6;
  const int lq = lane & 31;      // q column (and key/d row for frag reads)
  const int hi = lane >> 5;
  const int sw = lane & 7;       // row&7 for swizzle

  const int jb = blockIdx.x;     // 1024 blocks
  const int xcd = jb & 7;
  const int idx = jb >> 3;       // 0..127
  const int bh = xcd * 8 + (idx & 7);
  const int qt = idx >> 3;       // 0..15
  const int b = bh >> 5, h = bh & 31;
  const int kh = h >> 2;
  const size_t qbase = (size_t)bh * SLEN * HD;
  const size_t kbase = (size_t)(b * NKV + kh) * SLEN * HD;
  const size_t vbase = (size_t)(b * NKV + kh) * HD * SLEN;

  // Q fragments hoisted to registers: B[k=hd][col=q]
  const int q0 = qt * 128 + wid * 32;
  bf16x8 qf[4];
#pragma unroll
  for (int ks = 0; ks < 4; ++ks)
    qf[ks] = *(const bf16x8*)&qb[qbase + (size_t)(q0 + lq) * HD + ks * 16 + hi * 8];

  // staging: wave wid stages chunks {2*wid, 2*wid+1} of K and V (1KB each).
  // source pre-swizzled: chunk-col = (l&7) ^ ((l>>3)&7)  (row&7 == (l>>3)&7).
  const int ci0 = wid * 2;
  const int swzc = ((lane & 7) ^ ((lane >> 3) & 7)) * 8;
  const int srow = ci0 * 8 + (lane >> 3);
  const unsigned short* gk0 = kb + kbase + (size_t)srow * HD + swzc;
  const unsigned short* gk1 = gk0 + (size_t)8 * HD;
  const unsigned short* gv0 = vt + vbase + (size_t)srow * SLEN + swzc;
  const unsigned short* gv1 = gv0 + (size_t)8 * SLEN;

  f32x16 acc0 = {}, acc1 = {};
  float m = -1e30f, l = 0.f;

  // prologue: stage tile 0 into buffer 0
  gload_lds16(gk0, &Kbuf[0][ci0 * 512]);
  gload_lds16(gk1, &Kbuf[0][ci0 * 512 + 512]);
  gload_lds16(gv0, &Vbuf[0][ci0 * 512]);
  gload_lds16(gv1, &Vbuf[0][ci0 * 512 + 512]);

  for (int kt = 0; kt < SLEN / 64; ++kt) {
    const int cur = kt & 1;
    asm volatile("s_waitcnt vmcnt(0)" ::: "memory");
    __syncthreads();
    if (kt + 1 < SLEN / 64) {
      const int nxt = cur ^ 1;
      const size_t ko = (size_t)(kt + 1) * 64 * HD;
      const size_t vo = (size_t)(kt + 1) * 64;
      gload_lds16(gk0 + ko, &Kbuf[nxt][ci0 * 512]);
      gload_lds16(gk1 + ko, &Kbuf[nxt][ci0 * 512 + 512]);
      gload_lds16(gv0 + vo, &Vbuf[nxt][ci0 * 512]);
      gload_lds16(gv1 + vo, &Vbuf[nxt][ci0 * 512 + 512]);
    }

    // ---- QK^T: C[key][q], two 32-key subtiles ----
    f32x16 s0 = {}, s1 = {};
#pragma unroll
    for (int ks = 0; ks < 4; ++ks) {
      const bf16x8 kf = *(const bf16x8*)&Kbuf[cur][lq * HD + (((ks * 2 + hi) ^ sw) * 8)];
      s0 = __builtin_amdgcn_mfma_f32_32x32x16_bf16(kf, qf[ks], s0, 0, 0, 0);
    }
#pragma unroll
    for (int ks = 0; ks < 4; ++ks) {
      const bf16x8 kf = *(const bf16x8*)&Kbuf[cur][(32 + lq) * HD + (((ks * 2 + hi) ^ sw) * 8)];
      s1 = __builtin_amdgcn_mfma_f32_32x32x16_bf16(kf, qf[ks], s1, 0, 0, 0);
    }

    // ---- online softmax (exp2 domain), in-register ----
    float tm = s0[0];
#pragma unroll
    for (int i = 1; i < 16; ++i) tm = fmaxf(tm, s0[i]);
#pragma unroll
    for (int i = 0; i < 16; ++i) tm = fmaxf(tm, s1[i]);
    tm = fmaxf(tm, __shfl_xor(tm, 32));

    if (__any(tm > m + 8.0f)) {  // defer-max
      const float mn = fmaxf(m, tm);
      const float corr = fast_exp2(m - mn);
      l *= corr;
#pragma unroll
      for (int i = 0; i < 16; ++i) { acc0[i] *= corr; acc1[i] *= corr; }
      m = mn;
    }

    float p0[16], p1[16];
    float lsum = 0.f;
#pragma unroll
    for (int i = 0; i < 16; ++i) { p0[i] = fast_exp2(s0[i] - m); lsum += p0[i]; }
#pragma unroll
    for (int i = 0; i < 16; ++i) { p1[i] = fast_exp2(s1[i] - m); lsum += p1[i]; }
    lsum += __shfl_xor(lsum, 32);
    l += lsum;

    // ---- P -> bf16 B-frags via cvt_pk + permlane32_swap (no LDS) ----
    unsigned u0[8], u1[8];
#pragma unroll
    for (int c = 0; c < 4; ++c) {
      u0[2 * c] = cvt_pk_bf16(p0[4 * c], p0[4 * c + 1]);
      u0[2 * c + 1] = cvt_pk_bf16(p0[4 * c + 2], p0[4 * c + 3]);
      u1[2 * c] = cvt_pk_bf16(p1[4 * c], p1[4 * c + 1]);
      u1[2 * c + 1] = cvt_pk_bf16(p1[4 * c + 2], p1[4 * c + 3]);
    }
    bf16x8 pf[4];
    {
      unsigned a0 = u0[0], b0 = u0[2];
      asm volatile("v_permlane32_swap_b32 %0, %1" : "+v"(a0), "+v"(b0));
      unsigned a1 = u0[1], b1 = u0[3];
      asm volatile("v_permlane32_swap_b32 %0, %1" : "+v"(a1), "+v"(b1));
      u32x4 t = {a0, a1, b0, b1};
      pf[0] = __builtin_bit_cast(bf16x8, t);
      unsigned a2 = u0[4], b2 = u0[6];
      asm volatile("v_permlane32_swap_b32 %0, %1" : "+v"(a2), "+v"(b2));
      unsigned a3 = u0[5], b3 = u0[7];
      asm volatile("v_permlane32_swap_b32 %0, %1" : "+v"(a3), "+v"(b3));
      u32x4 t2 = {a2, a3, b2, b3};
      pf[1] = __builtin_bit_cast(bf16x8, t2);
      unsigned a4 = u1[0], b4 = u1[2];
      asm volatile("v_permlane32_swap_b32 %0, %1" : "+v"(a4), "+v"(b4));
      unsigned a5 = u1[1], b5 = u1[3];
      asm volatile("v_permlane32_swap_b32 %0, %1" : "+v"(a5), "+v"(b5));
      u32x4 t3 = {a4, a5, b4, b5};
      pf[2] = __builtin_bit_cast(bf16x8, t3);
      unsigned a6 = u1[4], b6 = u1[6];
      asm volatile("v_permlane32_swap_b32 %0, %1" : "+v"(a6), "+v"(b6));
      unsigned a7 = u1[5], b7 = u1[7];
      asm volatile("v_permlane32_swap_b32 %0, %1" : "+v"(a7), "+v"(b7));
      u32x4 t4 = {a6, a7, b6, b7};
      pf[3] = __builtin_bit_cast(bf16x8, t4);
    }

    // ---- PV: O^T[d][q] += V^T . P^T ----
#pragma unroll
    for (int ks = 0; ks < 4; ++ks) {
      const bf16x8 vf = *(const bf16x8*)&Vbuf[cur][lq * 64 + (((ks * 2 + hi) ^ sw) * 8)];
      acc0 = __builtin_amdgcn_mfma_f32_32x32x16_bf16(vf, pf[ks], acc0, 0, 0, 0);
    }
#pragma unroll
    for (int ks = 0; ks < 4; ++ks) {
      const bf16x8 vf = *(const bf16x8*)&Vbuf[cur][(32 + lq) * 64 + (((ks * 2 + hi) ^ sw) * 8)];
      acc1 = __builtin_amdgcn_mfma_f32_32x32x16_bf16(vf, pf[ks], acc1, 0, 0, 0);
    }
  }

  // ---- epilogue: d = dsub*32 + 8c + 4hi + (0..3), q = q0 + lq ----
  const float rl = 1.0f / l;
  const size_t obase = (size_t)(b * SLEN + q0 + lq) * DMODEL + h * HD;
#pragma unroll
  for (int c = 0; c < 4; ++c) {
    uint2 o;
    o.x = cvt_pk_bf16(acc0[4 * c] * rl, acc0[4 * c + 1] * rl);
    o.y = cvt_pk_bf16(acc0[4 * c + 2] * rl, acc0[4 * c + 3] * rl);
    *(uint2*)&aob[obase + 8 * c + 4 * hi] = o;
    uint2 o2;
    o2.x = cvt_pk_bf16(acc1[4 * c] * rl, acc1[4 * c + 1] * rl);
    o2.y = cvt_pk_bf16(acc1[4 * c + 2] * rl, acc1[4 * c + 3] * rl);
    *(uint2*)&aob[obase + 32 + 8 * c + 4 * hi] = o2;
  }
}

// ---------------------------------------------------------------------------
extern "C" void kernel_launch(void* const* d_in, const int* in_sizes, int n_in,
                              void* d_out, int out_size, void* d_ws, size_t ws_size,
                              hipStream_t stream) {
  const float* x  = (const float*)d_in[0];
  const float* Wq = (const float*)d_in[1];
  const float* Wk = (const float*)d_in[2];
  const float* Wv = (const float*)d_in[3];
  const float* Wo = (const float*)d_in[4];
  float* out = (float*)d_out;

  char* ws = (char*)d_ws;
  unsigned short* qkvb = (unsigned short*)ws; ws += (size_t)MROWS * QKVN * 2;             // 25.2 MB
  unsigned short* qb = (unsigned short*)ws;   ws += (size_t)BATCH * NH * SLEN * HD * 2;   // 16.8 MB
  unsigned short* kb = (unsigned short*)ws;   ws += (size_t)BATCH * NKV * SLEN * HD * 2;  //  4.2 MB
  unsigned short* vt = (unsigned short*)ws;   ws += (size_t)BATCH * NKV * HD * SLEN * 2;  //  4.2 MB
  unsigned short* xb = (unsigned short*)ws;   ws += (size_t)MROWS * DMODEL * 2;           // 16.8 MB
  unsigned short* aob = xb;  // aliases xb (dead after QKV GEMM)
  unsigned short* wqkvb = (unsigned short*)ws; ws += (size_t)QKVN * DMODEL * 2;           // 12.6 MB
  unsigned short* wob = (unsigned short*)ws;                                              //  8.4 MB

  dim3 blk(256);

  // ---- phase 1: bf16 conversions (2 launches) ----
  cvt_kernel<<<(MROWS * DMODEL / 8 + 255) / 256, blk, 0, stream>>>(x, xb, MROWS * DMODEL / 8);
  cvt_w4_kernel<<<(1310720 + 255) / 256, blk, 0, stream>>>(Wq, Wk, Wv, Wo, wqkvb, wob);

  // ---- fused QKV projection, bf16 out ----
  gemm_bf16_kernel<1><<<dim3(MROWS / 128, QKVN / 128), blk, 0, stream>>>(
      xb, wqkvb, qkvb, MROWS, QKVN, DMODEL);

  // ---- RoPE / layouts (bf16 in) ----
  rope_q_kernel<<<(BATCH * NH * SLEN * 32) / 256, blk, 0, stream>>>(qkvb, qb);
  rope_k_kernel<<<(BATCH * NKV * SLEN * 32) / 256, blk, 0, stream>>>(qkvb, kb);
  vcast_kernel<<<BATCH * NKV * (SLEN / 64), blk, 0, stream>>>(qkvb, vt);

  // ---- attention (writes bf16 aob; xb dead) ----
  attn_kernel<<<dim3(1024), blk, 0, stream>>>(qb, kb, vt, aob);

  // ---- output projection (bf16 in, fp32 out) ----
  gemm_bf16_kernel<0><<<dim3(MROWS / 128, DMODEL / 128), blk, 0, stream>>>(
      aob, wob, out, MROWS, DMODEL, DMODEL);
}